// Round 6
// baseline (620.628 us; speedup 1.0000x reference)
//
#include <hip/hip_runtime.h>
#include <hip/hip_bf16.h>

// ConvTSP gated-GCN forward, MI355X (gfx950). Round 6.
// B=4, N=200, H=128, L=3. f32 in/out, x_edges int32.
//
// Round-6 (byte diet): e residual stored BF16 (41 MB); e0 never
// materialized (layer-1 recomputes it from raw inputs: MODE2); etmp
// epilogue stores staged through a 4KB LDS tile -> full-line 16B global
// stores (round-5 counters showed write-allocate + partial-line RMW:
// MODE0 fetched 147 MB against ~5 MB logical). k_xupd folded into
// k_node_lin. LDS 20KB, launch_bounds(256,8).

typedef __hip_bfloat16 bf16;
typedef __attribute__((ext_vector_type(8))) short short8_t;
typedef __attribute__((ext_vector_type(4))) float f32x4;

#define B_ 4
#define N_ 200
#define H_ 128
#define BN_ (B_ * N_)
#define JT_ 4
#define NBLK_ (BN_ * JT_)
#define MAXROWS_ 64

__device__ __forceinline__ unsigned short f2b(float f) {
  unsigned int i = __float_as_uint(f);
  i = (i + 0x7fffu + ((i >> 16) & 1u)) >> 16;  // RNE
  return (unsigned short)i;
}
__device__ __forceinline__ float b2f16(unsigned short u) {
  return __uint_as_float((unsigned int)u << 16);
}

// ---------------- init ----------------

__global__ __launch_bounds__(128) void k_init_x(
    const float* __restrict__ coord, const float* __restrict__ w_coord,
    float* __restrict__ x) {
  int bi = blockIdx.x, h = threadIdx.x;
  float c0 = coord[bi * 2 + 0], c1 = coord[bi * 2 + 1];
  x[(size_t)bi * H_ + h] = c0 * w_coord[h] + c1 * w_coord[H_ + h];
}

__global__ __launch_bounds__(256) void k_cnt(const float* __restrict__ mask,
                                             float* __restrict__ cnts) {
  int t = threadIdx.x, b = t >> 6, l = t & 63;
  float s = 0.f;
  for (int n = l; n < N_; n += 64) s += mask[b * N_ + n];
#pragma unroll
  for (int d = 1; d < 64; d <<= 1) s += __shfl_xor(s, d);
  __shared__ float ms[B_];
  if (l == 0) ms[b] = s;
  __syncthreads();
  if (t == 0) {
    float cn = 0.f, ce = 0.f;
    for (int k = 0; k < B_; ++k) { cn += ms[k]; ce += ms[k] * ms[k]; }
    cnts[0] = cn; cnts[1] = ce;
  }
}

// transpose eU_w[0..2] and mlp_U_w into [out][in] bf16
__global__ __launch_bounds__(256) void k_prep_w(const float* __restrict__ eUw,
                                                const float* __restrict__ mUw,
                                                bf16* __restrict__ WT) {
  int blk = blockIdx.x;
  const float* src = (blk < 3) ? (eUw + (size_t)blk * H_ * H_) : mUw;
  bf16* dst = WT + (size_t)blk * H_ * H_;
  for (int q = threadIdx.x; q < H_ * H_; q += 256) {
    int out = q >> 7, in = q & 127;
    dst[q] = __float2bfloat16(src[in * H_ + out]);
  }
}

// ---------------- per-layer small: node linears (+fused x update) --------

template <int UPD>
__global__ __launch_bounds__(128) void k_node_lin(
    float* __restrict__ x, const float* __restrict__ xtmp,
    const float* __restrict__ ss, const float* __restrict__ eVw,
    const float* __restrict__ eVb, const float* __restrict__ nUw,
    const float* __restrict__ nUb, const float* __restrict__ nVw,
    const float* __restrict__ nVb, const float* __restrict__ mask,
    float* __restrict__ Vxe, float* __restrict__ Ux, float* __restrict__ Vx) {
  __shared__ float xr[H_];
  int bi = blockIdx.x, h = threadIdx.x;
  float m = mask[bi];
  float xv = x[(size_t)bi * H_ + h];
  if (UPD) {
    float tv = xtmp[(size_t)bi * H_ + h];
    float xn = (m > 0.f) ? fmaf(tv, ss[2 * H_ + h], ss[3 * H_ + h]) : tv;
    xv += fmaxf(xn, 0.f);
    x[(size_t)bi * H_ + h] = xv;
  }
  xr[h] = xv;
  __syncthreads();
  float a = 0.f, bvv = 0.f, c = 0.f;
#pragma unroll 4
  for (int k = 0; k < H_; ++k) {
    float kx = xr[k];
    a   = fmaf(kx, eVw[k * H_ + h], a);
    bvv = fmaf(kx, nUw[k * H_ + h], bvv);
    c   = fmaf(kx, nVw[k * H_ + h], c);
  }
  Vxe[(size_t)bi * H_ + h] = m * (a + eVb[h]);
  Ux[(size_t)bi * H_ + h]  = m * (bvv + nUb[h]);
  Vx[(size_t)bi * H_ + h]  = m * (c + nVb[h]);
}

// ---------------- big kernel: staged-update + GEMM + epilogue ------------
// grid = BN_*JT_. blockIdx -> (bi, jh). Block owns j-tiles [mt0,mt1).
// MODE 0: layer 0. A = e0 from raw inputs. No e write.
// MODE 2: layer 1. A = e1 = e0(recomputed from raw) + relu(bn(etmp)).
//         Writes e (bf16). Does not read e.
// MODE 1: layer 2. A = e + relu(bn(etmp)); e updated in place (bf16).

template <int MODE>
__global__ __launch_bounds__(256, 8) void k_edge(
    bf16* __restrict__ e, bf16* __restrict__ etmp,
    const float* __restrict__ ssPrev, const int* __restrict__ xe,
    const float* __restrict__ ev, const float* __restrict__ w_eval,
    const float* __restrict__ emb, const bf16* __restrict__ WT,
    const float* __restrict__ eUb, const float* __restrict__ Vxe,
    const float* __restrict__ Vx, const float* __restrict__ mask,
    float* __restrict__ pS, float* __restrict__ pAgg,
    float* __restrict__ pDen) {
  __shared__ __align__(16) char sA[MAXROWS_ * 256];
  __shared__ __align__(16) char sE[16 * 256];
  const int bi = blockIdx.x >> 2;
  const int jh = blockIdx.x & 3;
  const int mt0 = (jh == 0) ? 0 : 3 * jh + 1;
  const int mt1 = 3 * jh + 4;
  const int b = bi / N_;
  const int t = threadIdx.x;
  const int lane = t & 63;
  const int w = t >> 6;
  const float mask_i = mask[bi];

  // --- B fragments in registers (L2-hot WT) ---
  const int colA = (w << 5) + (lane & 15);
  const int colB = colA + 16;
  const int kgrp = (lane >> 4) << 3;
  short8_t bfA[4], bfB[4];
  {
    const short* w0 = (const short*)WT + colA * H_ + kgrp;
    const short* w1 = (const short*)WT + colB * H_ + kgrp;
#pragma unroll
    for (int kk = 0; kk < 4; ++kk) {
      bfA[kk] = *(const short8_t*)(w0 + kk * 32);
      bfB[kk] = *(const short8_t*)(w1 + kk * 32);
    }
  }

  // --- staging: build A tile rows [mt0*16, mt1*16) + fused e update ---
  {
    const int nrt = (mt1 - mt0) << 4;  // 48 or 64 rows
    unsigned short* eb = (unsigned short*)e + (size_t)bi * N_ * H_;
    const unsigned short* tb =
        (const unsigned short*)etmp + (size_t)bi * N_ * H_;
    for (int q4 = t; q4 < nrt * 32; q4 += 256) {
      int lr = q4 >> 5, k0 = (q4 & 31) << 2;
      int row = (mt0 << 4) + lr;
      float4 v = make_float4(0.f, 0.f, 0.f, 0.f);
      if (row < N_) {
        if (MODE == 0 || MODE == 2) {  // e0 from raw inputs
          if (k0 < 64) {
            float evv = ev[bi * N_ + row];
            v.x = evv * w_eval[k0 + 0];
            v.y = evv * w_eval[k0 + 1];
            v.z = evv * w_eval[k0 + 2];
            v.w = evv * w_eval[k0 + 3];
          } else {
            v = *(const float4*)(emb + xe[bi * N_ + row] * 64 + (k0 - 64));
          }
        } else {  // MODE 1: e from bf16 buffer
          ushort4 e4 = *(const ushort4*)(eb + row * H_ + k0);
          v.x = b2f16(e4.x); v.y = b2f16(e4.y);
          v.z = b2f16(e4.z); v.w = b2f16(e4.w);
        }
        if (MODE != 0) {  // + relu(bn(etmp_prev))
          ushort4 tv = *(const ushort4*)(tb + row * H_ + k0);
          float mj = mask[b * N_ + row];
          bool msk = (mask_i * mj) > 0.f;
          float4 sc = *(const float4*)(ssPrev + k0);
          float4 sh = *(const float4*)(ssPrev + H_ + k0);
          float f0 = b2f16(tv.x), f1 = b2f16(tv.y);
          float f2 = b2f16(tv.z), f3 = b2f16(tv.w);
          v.x += fmaxf(msk ? fmaf(f0, sc.x, sh.x) : f0, 0.f);
          v.y += fmaxf(msk ? fmaf(f1, sc.y, sh.y) : f1, 0.f);
          v.z += fmaxf(msk ? fmaf(f2, sc.z, sh.z) : f2, 0.f);
          v.w += fmaxf(msk ? fmaf(f3, sc.w, sh.w) : f3, 0.f);
        }
      }
      unsigned int p0 = ((unsigned int)f2b(v.y) << 16) | f2b(v.x);
      unsigned int p1 = ((unsigned int)f2b(v.w) << 16) | f2b(v.z);
      if (MODE != 0 && row < N_)
        *(uint2*)(eb + row * H_ + k0) = make_uint2(p0, p1);  // persist e_l
      unsigned long long pk = ((unsigned long long)p1 << 32) | p0;
      int byo = (lr << 8) + ((k0 * 2) ^ ((lr & 7) << 4));
      *(unsigned long long*)(sA + byo) = pk;
    }
  }
  __syncthreads();

  // --- GEMM + gate/agg/BN-partials epilogue (etmp via sE rebuffer) ---
  const float add0 = eUb[colA] + Vxe[(size_t)bi * H_ + colA];
  const float add1 = eUb[colB] + Vxe[(size_t)bi * H_ + colB];
  const float* VxeB = Vxe + (size_t)b * N_ * H_;
  const float* VxB  = Vx  + (size_t)b * N_ * H_;
  unsigned short* sEs = (unsigned short*)sE;

  float agg0 = 0.f, agg1 = 0.f, den0 = 0.f, den1 = 0.f;
  float s1a = 0.f, s1b = 0.f, s2a = 0.f, s2b = 0.f;
  const int kb = (lane >> 4) << 4;

  for (int mt = mt0; mt < mt1; ++mt) {
    f32x4 acc0 = {0.f, 0.f, 0.f, 0.f}, acc1 = {0.f, 0.f, 0.f, 0.f};
    int ra = ((mt - mt0) << 4) + (lane & 15);
#pragma unroll
    for (int kk = 0; kk < 4; ++kk) {
      int ko = kk * 64 + kb;
      short8_t av = *(const short8_t*)(sA + (ra << 8) + (ko ^ ((ra & 7) << 4)));
      acc0 = __builtin_amdgcn_mfma_f32_16x16x32_bf16(av, bfA[kk], acc0, 0, 0, 0);
      acc1 = __builtin_amdgcn_mfma_f32_16x16x32_bf16(av, bfB[kk], acc1, 0, 0, 0);
    }
#pragma unroll
    for (int r = 0; r < 4; ++r) {
      int rl = ((lane >> 4) << 2) + r;  // 0..15 within tile
      int j = (mt << 4) + rl;
      bool valid = (j < N_);
      float mj = valid ? mask[b * N_ + j] : 0.f;
      float sqm = mask_i * mj;
      float vj0 = valid ? VxeB[(size_t)j * H_ + colA] : 0.f;
      float vj1 = valid ? VxeB[(size_t)j * H_ + colB] : 0.f;
      float t0 = acc0[r] + add0 + vj0;
      float t1 = acc1[r] + add1 + vj1;
      sEs[rl * 128 + colA] = f2b(t0);
      sEs[rl * 128 + colB] = f2b(t1);
      float g0 = sqm / (1.f + __expf(-t0));
      float g1 = sqm / (1.f + __expf(-t1));
      float vx0 = valid ? VxB[(size_t)j * H_ + colA] : 0.f;
      float vx1 = valid ? VxB[(size_t)j * H_ + colB] : 0.f;
      agg0 = fmaf(g0, vx0, agg0);
      agg1 = fmaf(g1, vx1, agg1);
      den0 += g0; den1 += g1;
      s1a = fmaf(t0, sqm, s1a);
      s1b = fmaf(t1, sqm, s1b);
      s2a = fmaf(t0 * sqm, t0, s2a);
      s2b = fmaf(t1 * sqm, t1, s2b);
    }
    __syncthreads();
    {  // coalesced full-line etmp store: 256 threads x 16B
      int rl = t >> 4, c8 = (t & 15) << 3;
      int j = (mt << 4) + rl;
      if (j < N_)
        *(uint4*)((unsigned short*)etmp + ((size_t)bi * N_ + j) * H_ + c8) =
            *(const uint4*)(sE + rl * 256 + c8 * 2);
    }
    __syncthreads();
  }
#pragma unroll
  for (int d = 16; d <= 32; d <<= 1) {
    agg0 += __shfl_xor(agg0, d); agg1 += __shfl_xor(agg1, d);
    den0 += __shfl_xor(den0, d); den1 += __shfl_xor(den1, d);
    s1a += __shfl_xor(s1a, d);   s1b += __shfl_xor(s1b, d);
    s2a += __shfl_xor(s2a, d);   s2b += __shfl_xor(s2b, d);
  }
  if ((lane >> 4) == 0) {
    float* ps = pS + (size_t)blockIdx.x * 256;
    ps[colA] = s1a;
    ps[colB] = s1b;
    ps[128 + colA] = s2a;
    ps[128 + colB] = s2b;
    size_t po = ((size_t)jh * BN_ + bi) * H_;
    pAgg[po + colA] = agg0;
    pAgg[po + colB] = agg1;
    pDen[po + colA] = den0;
    pDen[po + colB] = den1;
  }
}

// ---------------- xtmp finalize (sum jh partials) ----------------

__global__ __launch_bounds__(128) void k_xfin(
    const float* __restrict__ pAgg, const float* __restrict__ pDen,
    const float* __restrict__ Ux, float* __restrict__ xtmp) {
  int bi = blockIdx.x, h = threadIdx.x;
  float a = 0.f, d = 0.f;
#pragma unroll
  for (int jh = 0; jh < JT_; ++jh) {
    a += pAgg[((size_t)jh * BN_ + bi) * H_ + h];
    d += pDen[((size_t)jh * BN_ + bi) * H_ + h];
  }
  xtmp[(size_t)bi * H_ + h] = Ux[(size_t)bi * H_ + h] + a / (1e-20f + d);
}

// ---------------- reduce partials -> sums (few atomics) ----------------

__global__ __launch_bounds__(256) void k_red(
    const float* __restrict__ pS, const float* __restrict__ xtmp,
    const float* __restrict__ mask, float* __restrict__ sums, int doN) {
  int g = blockIdx.x, t = threadIdx.x;
  if (g < 32) {
    float acc = 0.f;
    for (int blk = g * (NBLK_ / 32); blk < (g + 1) * (NBLK_ / 32); ++blk)
      acc += pS[(size_t)blk * 256 + t];
    atomicAdd(&sums[t], acc);
  } else if (doN) {
    int g2 = g - 32;
    int col = t & 127;
    bool sq = t >= 128;
    float acc = 0.f;
    for (int bi = g2 * (BN_ / 32); bi < (g2 + 1) * (BN_ / 32); ++bi) {
      float mi = mask[bi];
      float xt = xtmp[(size_t)bi * H_ + col];
      acc += (sq ? xt * xt : xt) * mi;
    }
    atomicAdd(&sums[256 + t], acc);
  }
}

// ---------------- BN finalize ----------------

__global__ __launch_bounds__(128) void k_stats(
    const float* __restrict__ sums, const float* __restrict__ cnts,
    const float* __restrict__ gE, const float* __restrict__ bE,
    const float* __restrict__ gN, const float* __restrict__ bN,
    float* __restrict__ ss) {
  int h = threadIdx.x;
  float cntN = cnts[0], cntE = cnts[1];
  float mE = sums[h] / cntE;
  float vE = sums[H_ + h] / cntE - mE * mE;
  float scE = gE[h] * rsqrtf(vE + 1e-5f);
  ss[h] = scE;
  ss[H_ + h] = bE[h] - mE * scE;
  float mN = sums[2 * H_ + h] / cntN;
  float vN = sums[3 * H_ + h] / cntN - mN * mN;
  float scN = gN[h] * rsqrtf(vN + 1e-5f);
  ss[2 * H_ + h] = scN;
  ss[3 * H_ + h] = bN[h] - mN * scN;
}

// ---------------- head: A = e + relu(bn(etmp)); y = relu(A@U+bU)@V + bV ---

__global__ __launch_bounds__(256, 8) void k_head(
    const bf16* __restrict__ e, const bf16* __restrict__ etmp,
    const float* __restrict__ ssPrev, const bf16* __restrict__ UT,
    const float* __restrict__ Ub, const float* __restrict__ Vw,
    const float* __restrict__ Vb, const float* __restrict__ mask,
    float* __restrict__ y) {
  __shared__ __align__(16) char sA[MAXROWS_ * 256];
  __shared__ float part[4][MAXROWS_][2];
  const int bi = blockIdx.x >> 2;
  const int jh = blockIdx.x & 3;
  const int mt0 = (jh == 0) ? 0 : 3 * jh + 1;
  const int mt1 = 3 * jh + 4;
  const int b = bi / N_;
  const int t = threadIdx.x;
  const int lane = t & 63;
  const int w = t >> 6;
  const float mask_i = mask[bi];

  const int colA = (w << 5) + (lane & 15);
  const int colB = colA + 16;
  const int kgrp = (lane >> 4) << 3;
  short8_t bfA[4], bfB[4];
  {
    const short* w0 = (const short*)UT + colA * H_ + kgrp;
    const short* w1 = (const short*)UT + colB * H_ + kgrp;
#pragma unroll
    for (int kk = 0; kk < 4; ++kk) {
      bfA[kk] = *(const short8_t*)(w0 + kk * 32);
      bfB[kk] = *(const short8_t*)(w1 + kk * 32);
    }
  }

  {
    const int nrt = (mt1 - mt0) << 4;
    const unsigned short* eb = (const unsigned short*)e + (size_t)bi * N_ * H_;
    const unsigned short* tb =
        (const unsigned short*)etmp + (size_t)bi * N_ * H_;
    for (int q4 = t; q4 < nrt * 32; q4 += 256) {
      int lr = q4 >> 5, k0 = (q4 & 31) << 2;
      int row = (mt0 << 4) + lr;
      float4 v = make_float4(0.f, 0.f, 0.f, 0.f);
      if (row < N_) {
        ushort4 e4 = *(const ushort4*)(eb + row * H_ + k0);
        ushort4 tv = *(const ushort4*)(tb + row * H_ + k0);
        float mj = mask[b * N_ + row];
        bool msk = (mask_i * mj) > 0.f;
        float4 sc = *(const float4*)(ssPrev + k0);
        float4 sh = *(const float4*)(ssPrev + H_ + k0);
        float f0 = b2f16(tv.x), f1 = b2f16(tv.y);
        float f2 = b2f16(tv.z), f3 = b2f16(tv.w);
        v.x = b2f16(e4.x) + fmaxf(msk ? fmaf(f0, sc.x, sh.x) : f0, 0.f);
        v.y = b2f16(e4.y) + fmaxf(msk ? fmaf(f1, sc.y, sh.y) : f1, 0.f);
        v.z = b2f16(e4.z) + fmaxf(msk ? fmaf(f2, sc.z, sh.z) : f2, 0.f);
        v.w = b2f16(e4.w) + fmaxf(msk ? fmaf(f3, sc.w, sh.w) : f3, 0.f);
      }
      unsigned int p0 = ((unsigned int)f2b(v.y) << 16) | f2b(v.x);
      unsigned int p1 = ((unsigned int)f2b(v.w) << 16) | f2b(v.z);
      unsigned long long pk = ((unsigned long long)p1 << 32) | p0;
      int byo = (lr << 8) + ((k0 * 2) ^ ((lr & 7) << 4));
      *(unsigned long long*)(sA + byo) = pk;
    }
  }
  __syncthreads();

  float bu0 = Ub[colA], bu1 = Ub[colB];
  float v00 = Vw[colA * 2], v01 = Vw[colA * 2 + 1];
  float v10 = Vw[colB * 2], v11 = Vw[colB * 2 + 1];
  const int kb = (lane >> 4) << 4;

  for (int mt = mt0; mt < mt1; ++mt) {
    f32x4 acc0 = {0.f, 0.f, 0.f, 0.f}, acc1 = {0.f, 0.f, 0.f, 0.f};
    int ra = ((mt - mt0) << 4) + (lane & 15);
#pragma unroll
    for (int kk = 0; kk < 4; ++kk) {
      int ko = kk * 64 + kb;
      short8_t av = *(const short8_t*)(sA + (ra << 8) + (ko ^ ((ra & 7) << 4)));
      acc0 = __builtin_amdgcn_mfma_f32_16x16x32_bf16(av, bfA[kk], acc0, 0, 0, 0);
      acc1 = __builtin_amdgcn_mfma_f32_16x16x32_bf16(av, bfB[kk], acc1, 0, 0, 0);
    }
#pragma unroll
    for (int r = 0; r < 4; ++r) {
      float h0v = fmaxf(acc0[r] + bu0, 0.f);
      float h1v = fmaxf(acc1[r] + bu1, 0.f);
      float p0 = h0v * v00 + h1v * v10;
      float p1 = h0v * v01 + h1v * v11;
#pragma unroll
      for (int d = 1; d < 16; d <<= 1) {
        p0 += __shfl_xor(p0, d);
        p1 += __shfl_xor(p1, d);
      }
      int jl = ((mt - mt0) << 4) + ((lane >> 4) << 2) + r;
      if ((lane & 15) == 0) { part[w][jl][0] = p0; part[w][jl][1] = p1; }
    }
  }
  __syncthreads();
  float vb0 = Vb[0], vb1 = Vb[1];
  const int nrt = (mt1 - mt0) << 4;
  for (int q = t; q < nrt * 2; q += 256) {
    int jl = q >> 1, c = q & 1;
    int j = (mt0 << 4) + jl;
    if (j < N_) {
      float s = part[0][jl][c] + part[1][jl][c] + part[2][jl][c] +
                part[3][jl][c] + (c ? vb1 : vb0);
      y[((size_t)bi * N_ + j) * 2 + c] = s;
    }
  }
}

// ---------------- launch ----------------

extern "C" void kernel_launch(void* const* d_in, const int* in_sizes, int n_in,
                              void* d_out, int out_size, void* d_ws,
                              size_t ws_size, hipStream_t stream) {
  const int*   x_edges = (const int*)d_in[0];
  const float* ev      = (const float*)d_in[1];
  const float* coord   = (const float*)d_in[2];
  const float* mask    = (const float*)d_in[3];
  const float* w_coord = (const float*)d_in[4];
  const float* w_eval  = (const float*)d_in[5];
  const float* emb     = (const float*)d_in[6];
  const float* eUw = (const float*)d_in[7];
  const float* eUb = (const float*)d_in[8];
  const float* eVw = (const float*)d_in[9];
  const float* eVb = (const float*)d_in[10];
  const float* nUw = (const float*)d_in[11];
  const float* nUb = (const float*)d_in[12];
  const float* nVw = (const float*)d_in[13];
  const float* nVb = (const float*)d_in[14];
  const float* gE  = (const float*)d_in[15];
  const float* bE  = (const float*)d_in[16];
  const float* gN  = (const float*)d_in[17];
  const float* bN  = (const float*)d_in[18];
  const float* mUw = (const float*)d_in[19];
  const float* mUb = (const float*)d_in[20];
  const float* mVw = (const float*)d_in[21];
  const float* mVb = (const float*)d_in[22];

  char* ws = (char*)d_ws;
  size_t off = 0;
  auto alloc = [&](size_t bytes) {
    void* p = ws + off;
    off += (bytes + 255) & ~(size_t)255;
    return p;
  };
  bf16* e     = (bf16*)alloc((size_t)B_ * N_ * N_ * H_ * 2);   // 40.96 MB
  bf16* etmp  = (bf16*)alloc((size_t)B_ * N_ * N_ * H_ * 2);   // 40.96 MB
  float* x    = (float*)alloc((size_t)BN_ * H_ * 4);
  float* Vxe  = (float*)alloc((size_t)BN_ * H_ * 4);
  float* Ux   = (float*)alloc((size_t)BN_ * H_ * 4);
  float* Vx   = (float*)alloc((size_t)BN_ * H_ * 4);
  float* xtmp = (float*)alloc((size_t)BN_ * H_ * 4);
  float* pS   = (float*)alloc((size_t)NBLK_ * 256 * 4);        // 3.28 MB
  float* pAgg = (float*)alloc((size_t)JT_ * BN_ * H_ * 4);     // 1.64 MB
  float* pDen = (float*)alloc((size_t)JT_ * BN_ * H_ * 4);     // 1.64 MB
  float* sums = (float*)alloc(4 * H_ * 4);
  float* ss   = (float*)alloc(4 * H_ * 4);
  float* cnts = (float*)alloc(256);
  bf16* WT    = (bf16*)alloc((size_t)4 * H_ * H_ * 2);

  k_prep_w<<<4, 256, 0, stream>>>(eUw, mUw, WT);
  k_init_x<<<BN_, 128, 0, stream>>>(coord, w_coord, x);
  k_cnt<<<1, 256, 0, stream>>>(mask, cnts);

  for (int l = 0; l < 3; ++l) {
    size_t wo = (size_t)l * H_ * H_;
    size_t bo = (size_t)l * H_;
    hipMemsetAsync(sums, 0, 4 * H_ * 4, stream);
    if (l == 0)
      k_node_lin<0><<<BN_, 128, 0, stream>>>(x, xtmp, ss, eVw + wo, eVb + bo,
                                             nUw + wo, nUb + bo, nVw + wo,
                                             nVb + bo, mask, Vxe, Ux, Vx);
    else
      k_node_lin<1><<<BN_, 128, 0, stream>>>(x, xtmp, ss, eVw + wo, eVb + bo,
                                             nUw + wo, nUb + bo, nVw + wo,
                                             nVb + bo, mask, Vxe, Ux, Vx);
    if (l == 0)
      k_edge<0><<<NBLK_, 256, 0, stream>>>(e, etmp, ss, x_edges, ev, w_eval,
                                           emb, WT + wo, eUb + bo, Vxe, Vx,
                                           mask, pS, pAgg, pDen);
    else if (l == 1)
      k_edge<2><<<NBLK_, 256, 0, stream>>>(e, etmp, ss, x_edges, ev, w_eval,
                                           emb, WT + wo, eUb + bo, Vxe, Vx,
                                           mask, pS, pAgg, pDen);
    else
      k_edge<1><<<NBLK_, 256, 0, stream>>>(e, etmp, ss, x_edges, ev, w_eval,
                                           emb, WT + wo, eUb + bo, Vxe, Vx,
                                           mask, pS, pAgg, pDen);
    if (l < 2)
      k_xfin<<<BN_, 128, 0, stream>>>(pAgg, pDen, Ux, xtmp);
    k_red<<<64, 256, 0, stream>>>(pS, xtmp, mask, sums, (l < 2) ? 1 : 0);
    k_stats<<<1, 128, 0, stream>>>(sums, cnts, gE + bo, bE + bo, gN + bo,
                                   bN + bo, ss);
  }
  k_head<<<NBLK_, 256, 0, stream>>>(e, etmp, ss, WT + (size_t)3 * H_ * H_,
                                    mUb, mVw, mVb, mask, (float*)d_out);
}

// Round 7
// 472.495 us; speedup vs baseline: 1.3135x; 1.3135x over previous
//
#include <hip/hip_runtime.h>
#include <hip/hip_bf16.h>

// ConvTSP gated-GCN forward, MI355X (gfx950). Round 7.
// B=4, N=200, H=128, L=3. f32 in/out, x_edges int32.
//
// Structure: REVERT to round-3 monolithic per-bi blocks (grid 800) -- the
// only config whose HBM bytes matched logical (L3 absorbs the inter-layer
// e/etmp streams). j-split variants inflated HBM 2-3x. On top of R3:
//  - e stored bf16; e0 never materialized (MODE0 no e-write, MODE2
//    recomputes e0 from raw inputs).
//  - Vxe/Vx epilogue loads software-pipelined (prefetch mt+1 during mt).
//  - 16-B staging loads/LDS writes (k0 constant per thread; ss/w_eval
//    hoisted to registers).
//  - k_stats/k_xupd/k_xfin/k_red eliminated: ss computed inline from
//    sums (L2-hot) in k_node_lin / k_edge / k_head; BN sums via R3-scale
//    atomics into per-layer sums buffers (zeroed once per call).

typedef __hip_bfloat16 bf16;
typedef __attribute__((ext_vector_type(8))) short short8_t;
typedef __attribute__((ext_vector_type(4))) float f32x4;

#define B_ 4
#define N_ 200
#define H_ 128
#define BN_ (B_ * N_)
#define MT_ 13
#define MROWS_ 208

__device__ __forceinline__ unsigned short f2b(float f) {
  unsigned int i = __float_as_uint(f);
  i = (i + 0x7fffu + ((i >> 16) & 1u)) >> 16;  // RNE
  return (unsigned short)i;
}
__device__ __forceinline__ float b2f16(unsigned short u) {
  return __uint_as_float((unsigned int)u << 16);
}

// ---------------- init ----------------

__global__ __launch_bounds__(128) void k_init_x(
    const float* __restrict__ coord, const float* __restrict__ w_coord,
    float* __restrict__ x) {
  int bi = blockIdx.x, h = threadIdx.x;
  float c0 = coord[bi * 2 + 0], c1 = coord[bi * 2 + 1];
  x[(size_t)bi * H_ + h] = c0 * w_coord[h] + c1 * w_coord[H_ + h];
}

__global__ __launch_bounds__(256) void k_cnt(const float* __restrict__ mask,
                                             float* __restrict__ cnts) {
  int t = threadIdx.x, b = t >> 6, l = t & 63;
  float s = 0.f;
  for (int n = l; n < N_; n += 64) s += mask[b * N_ + n];
#pragma unroll
  for (int d = 1; d < 64; d <<= 1) s += __shfl_xor(s, d);
  __shared__ float ms[B_];
  if (l == 0) ms[b] = s;
  __syncthreads();
  if (t == 0) {
    float cn = 0.f, ce = 0.f;
    for (int k = 0; k < B_; ++k) { cn += ms[k]; ce += ms[k] * ms[k]; }
    cnts[0] = cn; cnts[1] = ce;
  }
}

// transpose eU_w[0..2] and mlp_U_w into [out][in] bf16
__global__ __launch_bounds__(256) void k_prep_w(const float* __restrict__ eUw,
                                                const float* __restrict__ mUw,
                                                bf16* __restrict__ WT) {
  int blk = blockIdx.x;
  const float* src = (blk < 3) ? (eUw + (size_t)blk * H_ * H_) : mUw;
  bf16* dst = WT + (size_t)blk * H_ * H_;
  for (int q = threadIdx.x; q < H_ * H_; q += 256) {
    int out = q >> 7, in = q & 127;
    dst[q] = __float2bfloat16(src[in * H_ + out]);
  }
}

// ---------------- node linears (+fused x update, inline ssN) ----------------

template <int UPD>
__global__ __launch_bounds__(128) void k_node_lin(
    float* __restrict__ x, const float* __restrict__ xtmp,
    const float* __restrict__ sumsPrev, const float* __restrict__ cnts,
    const float* __restrict__ gNp, const float* __restrict__ bNp,
    const float* __restrict__ eVw, const float* __restrict__ eVb,
    const float* __restrict__ nUw, const float* __restrict__ nUb,
    const float* __restrict__ nVw, const float* __restrict__ nVb,
    const float* __restrict__ mask, float* __restrict__ Vxe,
    float* __restrict__ Ux, float* __restrict__ Vx) {
  __shared__ float xr[H_];
  int bi = blockIdx.x, h = threadIdx.x;
  float m = mask[bi];
  float xv = x[(size_t)bi * H_ + h];
  if (UPD) {
    float cntN = cnts[0];
    float mN = sumsPrev[256 + h] / cntN;
    float vN = sumsPrev[384 + h] / cntN - mN * mN;
    float scN = gNp[h] * rsqrtf(vN + 1e-5f);
    float shN = bNp[h] - mN * scN;
    float tv = xtmp[(size_t)bi * H_ + h];
    float xn = (m > 0.f) ? fmaf(tv, scN, shN) : tv;
    xv += fmaxf(xn, 0.f);
    x[(size_t)bi * H_ + h] = xv;
  }
  xr[h] = xv;
  __syncthreads();
  float a = 0.f, bvv = 0.f, c = 0.f;
#pragma unroll 4
  for (int k = 0; k < H_; ++k) {
    float kx = xr[k];
    a   = fmaf(kx, eVw[k * H_ + h], a);
    bvv = fmaf(kx, nUw[k * H_ + h], bvv);
    c   = fmaf(kx, nVw[k * H_ + h], c);
  }
  Vxe[(size_t)bi * H_ + h] = m * (a + eVb[h]);
  Ux[(size_t)bi * H_ + h]  = m * (bvv + nUb[h]);
  Vx[(size_t)bi * H_ + h]  = m * (c + nVb[h]);
}

// ---------------- epilogue prefetch helper ----------------

__device__ __forceinline__ void load_pre(int mt, int jg, int bN, float mask_i,
                                         const float* __restrict__ mask,
                                         const float* __restrict__ VxeB,
                                         const float* __restrict__ VxB,
                                         int colA, int colB, float* vj0,
                                         float* vj1, float* vx0, float* vx1,
                                         float* sq) {
#pragma unroll
  for (int r = 0; r < 4; ++r) {
    int j = (mt << 4) + jg + r;
    bool valid = (j < N_);
    float mj = valid ? mask[bN + j] : 0.f;
    sq[r] = mask_i * mj;
    vj0[r] = valid ? VxeB[(size_t)j * H_ + colA] : 0.f;
    vj1[r] = valid ? VxeB[(size_t)j * H_ + colB] : 0.f;
    vx0[r] = valid ? VxB[(size_t)j * H_ + colA] : 0.f;
    vx1[r] = valid ? VxB[(size_t)j * H_ + colB] : 0.f;
  }
}

// ---------------- big kernel: staged-update + GEMM + epilogue ------------
// MODE 0: layer 0. A = e0 from raw inputs. No e write.
// MODE 2: layer 1. A = e0(recomputed) + relu(bnE(etmp)). Writes e (bf16).
// MODE 1: layer 2. A = e + relu(bnE(etmp)); e updated in place.
// ssE computed inline from sumsPrev; BN sums atomically into sumsCur.

template <int MODE, bool DO_X>
__global__ __launch_bounds__(256, 3) void k_edge(
    bf16* __restrict__ e, bf16* __restrict__ etmp,
    const float* __restrict__ sumsPrev, const float* __restrict__ cnts,
    const float* __restrict__ gEp, const float* __restrict__ bEp,
    const int* __restrict__ xe, const float* __restrict__ ev,
    const float* __restrict__ w_eval, const float* __restrict__ emb,
    const bf16* __restrict__ WT, const float* __restrict__ eUb,
    const float* __restrict__ Vxe, const float* __restrict__ Vx,
    const float* __restrict__ Ux, const float* __restrict__ mask,
    float* __restrict__ xtmp, float* __restrict__ sumsCur) {
  __shared__ __align__(16) char sA[MROWS_ * 256];
  __shared__ float ssE_s[256];
  const int bi = blockIdx.x;
  const int b = bi / N_;
  const int t = threadIdx.x;
  const int lane = t & 63;
  const int w = t >> 6;
  const float mask_i = mask[bi];

  // inline ssE from previous layer's sums (L2-hot, 2KB)
  if (MODE != 0) {
    int h = t & 127;
    float cntE = cnts[1];
    float mE = sumsPrev[h] / cntE;
    float vE = sumsPrev[128 + h] / cntE - mE * mE;
    float scE = gEp[h] * rsqrtf(vE + 1e-5f);
    ssE_s[t] = (t < 128) ? scE : (bEp[h] - mE * scE);
    __syncthreads();
  }

  // --- B fragments in registers (L2-hot WT) ---
  const int colA = (w << 5) + (lane & 15);
  const int colB = colA + 16;
  const int kgrp = (lane >> 4) << 3;
  short8_t bfA[4], bfB[4];
  {
    const short* w0 = (const short*)WT + colA * H_ + kgrp;
    const short* w1 = (const short*)WT + colB * H_ + kgrp;
#pragma unroll
    for (int kk = 0; kk < 4; ++kk) {
      bfA[kk] = *(const short8_t*)(w0 + kk * 32);
      bfB[kk] = *(const short8_t*)(w1 + kk * 32);
    }
  }

  // --- staging: 16B/thread/iter; k0 constant per thread ---
  {
    const int k0 = (t & 15) << 3;   // 8-channel group, constant
    const int lr0 = t >> 4;         // row stride 16
    float scr[8], shr[8], we[8];
    if (MODE != 0) {
#pragma unroll
      for (int c = 0; c < 8; ++c) {
        scr[c] = ssE_s[k0 + c];
        shr[c] = ssE_s[128 + k0 + c];
      }
    }
    if ((MODE == 0 || MODE == 2) && k0 < 64) {
#pragma unroll
      for (int c = 0; c < 8; ++c) we[c] = w_eval[k0 + c];
    }
    unsigned short* eb = (unsigned short*)e + (size_t)bi * N_ * H_;
    const unsigned short* tb =
        (const unsigned short*)etmp + (size_t)bi * N_ * H_;
#pragma unroll
    for (int n = 0; n < 13; ++n) {
      int row = lr0 + (n << 4);
      float v[8];
#pragma unroll
      for (int c = 0; c < 8; ++c) v[c] = 0.f;
      if (row < N_) {
        if (MODE == 0 || MODE == 2) {
          if (k0 < 64) {
            float evv = ev[bi * N_ + row];
#pragma unroll
            for (int c = 0; c < 8; ++c) v[c] = evv * we[c];
          } else {
            const float* em = emb + xe[bi * N_ + row] * 64 + (k0 - 64);
            float4 a4 = *(const float4*)em;
            float4 b4 = *(const float4*)(em + 4);
            v[0] = a4.x; v[1] = a4.y; v[2] = a4.z; v[3] = a4.w;
            v[4] = b4.x; v[5] = b4.y; v[6] = b4.z; v[7] = b4.w;
          }
        } else {
          uint4 e8 = *(const uint4*)(eb + row * H_ + k0);
          v[0] = b2f16((unsigned short)e8.x);
          v[1] = b2f16((unsigned short)(e8.x >> 16));
          v[2] = b2f16((unsigned short)e8.y);
          v[3] = b2f16((unsigned short)(e8.y >> 16));
          v[4] = b2f16((unsigned short)e8.z);
          v[5] = b2f16((unsigned short)(e8.z >> 16));
          v[6] = b2f16((unsigned short)e8.w);
          v[7] = b2f16((unsigned short)(e8.w >> 16));
        }
        if (MODE != 0) {
          uint4 t8 = *(const uint4*)(tb + row * H_ + k0);
          float mj = mask[b * N_ + row];
          bool msk = (mask_i * mj) > 0.f;
          unsigned short tu[8] = {
              (unsigned short)t8.x, (unsigned short)(t8.x >> 16),
              (unsigned short)t8.y, (unsigned short)(t8.y >> 16),
              (unsigned short)t8.z, (unsigned short)(t8.z >> 16),
              (unsigned short)t8.w, (unsigned short)(t8.w >> 16)};
#pragma unroll
          for (int c = 0; c < 8; ++c) {
            float f = b2f16(tu[c]);
            float xn = msk ? fmaf(f, scr[c], shr[c]) : f;
            v[c] += fmaxf(xn, 0.f);
          }
        }
      }
      uint4 pk;
      pk.x = ((unsigned int)f2b(v[1]) << 16) | f2b(v[0]);
      pk.y = ((unsigned int)f2b(v[3]) << 16) | f2b(v[2]);
      pk.z = ((unsigned int)f2b(v[5]) << 16) | f2b(v[4]);
      pk.w = ((unsigned int)f2b(v[7]) << 16) | f2b(v[6]);
      if (MODE != 0 && row < N_)
        *(uint4*)(eb + row * H_ + k0) = pk;  // persist e_l
      int byo = (row << 8) + ((k0 * 2) ^ ((row & 7) << 4));
      *(uint4*)(sA + byo) = pk;
    }
  }
  __syncthreads();

  // --- GEMM + gate/agg/BN epilogue, Vxe/Vx prefetch pipeline ---
  const float add0 = eUb[colA] + Vxe[(size_t)bi * H_ + colA];
  const float add1 = eUb[colB] + Vxe[(size_t)bi * H_ + colB];
  const float* VxeB = Vxe + (size_t)b * N_ * H_;
  const float* VxB  = Vx  + (size_t)b * N_ * H_;
  const int bN = b * N_;
  const int jg = (lane >> 4) << 2;
  const int kb = (lane >> 4) << 4;

  float agg0 = 0.f, agg1 = 0.f, den0 = 0.f, den1 = 0.f;
  float s1a = 0.f, s1b = 0.f, s2a = 0.f, s2b = 0.f;

  float cvj0[4], cvj1[4], cvx0[4], cvx1[4], csq[4];
  float nvj0[4], nvj1[4], nvx0[4], nvx1[4], nsq[4];
  load_pre(0, jg, bN, mask_i, mask, VxeB, VxB, colA, colB, cvj0, cvj1, cvx0,
           cvx1, csq);

#pragma unroll
  for (int mt = 0; mt < MT_; ++mt) {
    f32x4 acc0 = {0.f, 0.f, 0.f, 0.f}, acc1 = {0.f, 0.f, 0.f, 0.f};
    int ra = (mt << 4) + (lane & 15);
#pragma unroll
    for (int kk = 0; kk < 4; ++kk) {
      int ko = kk * 64 + kb;
      short8_t av = *(const short8_t*)(sA + (ra << 8) + (ko ^ ((ra & 7) << 4)));
      acc0 = __builtin_amdgcn_mfma_f32_16x16x32_bf16(av, bfA[kk], acc0, 0, 0, 0);
      acc1 = __builtin_amdgcn_mfma_f32_16x16x32_bf16(av, bfB[kk], acc1, 0, 0, 0);
    }
    if (mt < MT_ - 1)
      load_pre(mt + 1, jg, bN, mask_i, mask, VxeB, VxB, colA, colB, nvj0,
               nvj1, nvx0, nvx1, nsq);
#pragma unroll
    for (int r = 0; r < 4; ++r) {
      int j = (mt << 4) + jg + r;
      float sqm = csq[r];
      float t0 = acc0[r] + add0 + cvj0[r];
      float t1 = acc1[r] + add1 + cvj1[r];
      if (j < N_) {
        size_t o = ((size_t)bi * N_ + j) * H_;
        ((unsigned short*)etmp)[o + colA] = f2b(t0);
        ((unsigned short*)etmp)[o + colB] = f2b(t1);
      }
      float g0 = sqm / (1.f + __expf(-t0));
      float g1 = sqm / (1.f + __expf(-t1));
      agg0 = fmaf(g0, cvx0[r], agg0);
      agg1 = fmaf(g1, cvx1[r], agg1);
      den0 += g0; den1 += g1;
      s1a = fmaf(t0, sqm, s1a);
      s1b = fmaf(t1, sqm, s1b);
      s2a = fmaf(t0 * sqm, t0, s2a);
      s2b = fmaf(t1 * sqm, t1, s2b);
    }
#pragma unroll
    for (int r = 0; r < 4; ++r) {
      cvj0[r] = nvj0[r]; cvj1[r] = nvj1[r];
      cvx0[r] = nvx0[r]; cvx1[r] = nvx1[r];
      csq[r] = nsq[r];
    }
  }
#pragma unroll
  for (int d = 16; d <= 32; d <<= 1) {
    agg0 += __shfl_xor(agg0, d); agg1 += __shfl_xor(agg1, d);
    den0 += __shfl_xor(den0, d); den1 += __shfl_xor(den1, d);
    s1a += __shfl_xor(s1a, d);   s1b += __shfl_xor(s1b, d);
    s2a += __shfl_xor(s2a, d);   s2b += __shfl_xor(s2b, d);
  }
  if ((lane >> 4) == 0) {
    atomicAdd(&sumsCur[colA], s1a);
    atomicAdd(&sumsCur[colB], s1b);
    atomicAdd(&sumsCur[128 + colA], s2a);
    atomicAdd(&sumsCur[128 + colB], s2b);
    if (DO_X) {
      float xt0 = Ux[(size_t)bi * H_ + colA] + agg0 / (1e-20f + den0);
      float xt1 = Ux[(size_t)bi * H_ + colB] + agg1 / (1e-20f + den1);
      xtmp[(size_t)bi * H_ + colA] = xt0;
      xtmp[(size_t)bi * H_ + colB] = xt1;
      atomicAdd(&sumsCur[256 + colA], xt0 * mask_i);
      atomicAdd(&sumsCur[384 + colA], xt0 * xt0 * mask_i);
      atomicAdd(&sumsCur[256 + colB], xt1 * mask_i);
      atomicAdd(&sumsCur[384 + colB], xt1 * xt1 * mask_i);
    }
  }
}

// ---------------- head: A = e + relu(bnE(etmp)); y = relu(A@U+bU)@V + bV ---

__global__ __launch_bounds__(256, 2) void k_head(
    const bf16* __restrict__ e, const bf16* __restrict__ etmp,
    const float* __restrict__ sumsPrev, const float* __restrict__ cnts,
    const float* __restrict__ gEp, const float* __restrict__ bEp,
    const bf16* __restrict__ UT, const float* __restrict__ Ub,
    const float* __restrict__ Vw, const float* __restrict__ Vb,
    const float* __restrict__ mask, float* __restrict__ y) {
  __shared__ __align__(16) char sA[MROWS_ * 256];
  __shared__ float part[4][MROWS_][2];
  __shared__ float ssE_s[256];
  const int bi = blockIdx.x;
  const int b = bi / N_;
  const int t = threadIdx.x;
  const int lane = t & 63;
  const int w = t >> 6;
  const float mask_i = mask[bi];

  {
    int h = t & 127;
    float cntE = cnts[1];
    float mE = sumsPrev[h] / cntE;
    float vE = sumsPrev[128 + h] / cntE - mE * mE;
    float scE = gEp[h] * rsqrtf(vE + 1e-5f);
    ssE_s[t] = (t < 128) ? scE : (bEp[h] - mE * scE);
    __syncthreads();
  }

  const int colA = (w << 5) + (lane & 15);
  const int colB = colA + 16;
  const int kgrp = (lane >> 4) << 3;
  short8_t bfA[4], bfB[4];
  {
    const short* w0 = (const short*)UT + colA * H_ + kgrp;
    const short* w1 = (const short*)UT + colB * H_ + kgrp;
#pragma unroll
    for (int kk = 0; kk < 4; ++kk) {
      bfA[kk] = *(const short8_t*)(w0 + kk * 32);
      bfB[kk] = *(const short8_t*)(w1 + kk * 32);
    }
  }

  {
    const int k0 = (t & 15) << 3;
    const int lr0 = t >> 4;
    float scr[8], shr[8];
#pragma unroll
    for (int c = 0; c < 8; ++c) {
      scr[c] = ssE_s[k0 + c];
      shr[c] = ssE_s[128 + k0 + c];
    }
    const unsigned short* eb = (const unsigned short*)e + (size_t)bi * N_ * H_;
    const unsigned short* tb =
        (const unsigned short*)etmp + (size_t)bi * N_ * H_;
#pragma unroll
    for (int n = 0; n < 13; ++n) {
      int row = lr0 + (n << 4);
      float v[8];
#pragma unroll
      for (int c = 0; c < 8; ++c) v[c] = 0.f;
      if (row < N_) {
        uint4 e8 = *(const uint4*)(eb + row * H_ + k0);
        uint4 t8 = *(const uint4*)(tb + row * H_ + k0);
        float mj = mask[b * N_ + row];
        bool msk = (mask_i * mj) > 0.f;
        unsigned short eu[8] = {
            (unsigned short)e8.x, (unsigned short)(e8.x >> 16),
            (unsigned short)e8.y, (unsigned short)(e8.y >> 16),
            (unsigned short)e8.z, (unsigned short)(e8.z >> 16),
            (unsigned short)e8.w, (unsigned short)(e8.w >> 16)};
        unsigned short tu[8] = {
            (unsigned short)t8.x, (unsigned short)(t8.x >> 16),
            (unsigned short)t8.y, (unsigned short)(t8.y >> 16),
            (unsigned short)t8.z, (unsigned short)(t8.z >> 16),
            (unsigned short)t8.w, (unsigned short)(t8.w >> 16)};
#pragma unroll
        for (int c = 0; c < 8; ++c) {
          float f = b2f16(tu[c]);
          float xn = msk ? fmaf(f, scr[c], shr[c]) : f;
          v[c] = b2f16(eu[c]) + fmaxf(xn, 0.f);
        }
      }
      uint4 pk;
      pk.x = ((unsigned int)f2b(v[1]) << 16) | f2b(v[0]);
      pk.y = ((unsigned int)f2b(v[3]) << 16) | f2b(v[2]);
      pk.z = ((unsigned int)f2b(v[5]) << 16) | f2b(v[4]);
      pk.w = ((unsigned int)f2b(v[7]) << 16) | f2b(v[6]);
      int byo = (row << 8) + ((k0 * 2) ^ ((row & 7) << 4));
      *(uint4*)(sA + byo) = pk;
    }
  }
  __syncthreads();

  float bu0 = Ub[colA], bu1 = Ub[colB];
  float v00 = Vw[colA * 2], v01 = Vw[colA * 2 + 1];
  float v10 = Vw[colB * 2], v11 = Vw[colB * 2 + 1];
  const int kb = (lane >> 4) << 4;

  for (int mt = 0; mt < MT_; ++mt) {
    f32x4 acc0 = {0.f, 0.f, 0.f, 0.f}, acc1 = {0.f, 0.f, 0.f, 0.f};
    int ra = (mt << 4) + (lane & 15);
#pragma unroll
    for (int kk = 0; kk < 4; ++kk) {
      int ko = kk * 64 + kb;
      short8_t av = *(const short8_t*)(sA + (ra << 8) + (ko ^ ((ra & 7) << 4)));
      acc0 = __builtin_amdgcn_mfma_f32_16x16x32_bf16(av, bfA[kk], acc0, 0, 0, 0);
      acc1 = __builtin_amdgcn_mfma_f32_16x16x32_bf16(av, bfB[kk], acc1, 0, 0, 0);
    }
#pragma unroll
    for (int r = 0; r < 4; ++r) {
      float h0v = fmaxf(acc0[r] + bu0, 0.f);
      float h1v = fmaxf(acc1[r] + bu1, 0.f);
      float p0 = h0v * v00 + h1v * v10;
      float p1 = h0v * v01 + h1v * v11;
#pragma unroll
      for (int d = 1; d < 16; d <<= 1) {
        p0 += __shfl_xor(p0, d);
        p1 += __shfl_xor(p1, d);
      }
      int jl = (mt << 4) + ((lane >> 4) << 2) + r;
      if ((lane & 15) == 0) { part[w][jl][0] = p0; part[w][jl][1] = p1; }
    }
  }
  __syncthreads();
  float vb0 = Vb[0], vb1 = Vb[1];
  for (int q = t; q < N_ * 2; q += 256) {
    int j = q >> 1, c = q & 1;
    float s = part[0][j][c] + part[1][j][c] + part[2][j][c] + part[3][j][c] +
              (c ? vb1 : vb0);
    y[((size_t)bi * N_ + j) * 2 + c] = s;
  }
}

// ---------------- launch ----------------

extern "C" void kernel_launch(void* const* d_in, const int* in_sizes, int n_in,
                              void* d_out, int out_size, void* d_ws,
                              size_t ws_size, hipStream_t stream) {
  const int*   x_edges = (const int*)d_in[0];
  const float* ev      = (const float*)d_in[1];
  const float* coord   = (const float*)d_in[2];
  const float* mask    = (const float*)d_in[3];
  const float* w_coord = (const float*)d_in[4];
  const float* w_eval  = (const float*)d_in[5];
  const float* emb     = (const float*)d_in[6];
  const float* eUw = (const float*)d_in[7];
  const float* eUb = (const float*)d_in[8];
  const float* eVw = (const float*)d_in[9];
  const float* eVb = (const float*)d_in[10];
  const float* nUw = (const float*)d_in[11];
  const float* nUb = (const float*)d_in[12];
  const float* nVw = (const float*)d_in[13];
  const float* nVb = (const float*)d_in[14];
  const float* gE  = (const float*)d_in[15];
  const float* bE  = (const float*)d_in[16];
  const float* gN  = (const float*)d_in[17];
  const float* bN  = (const float*)d_in[18];
  const float* mUw = (const float*)d_in[19];
  const float* mUb = (const float*)d_in[20];
  const float* mVw = (const float*)d_in[21];
  const float* mVb = (const float*)d_in[22];

  char* ws = (char*)d_ws;
  size_t off = 0;
  auto alloc = [&](size_t bytes) {
    void* p = ws + off;
    off += (bytes + 255) & ~(size_t)255;
    return p;
  };
  bf16* e     = (bf16*)alloc((size_t)B_ * N_ * N_ * H_ * 2);   // 40.96 MB
  bf16* etmp  = (bf16*)alloc((size_t)B_ * N_ * N_ * H_ * 2);   // 40.96 MB
  float* x    = (float*)alloc((size_t)BN_ * H_ * 4);
  float* Vxe  = (float*)alloc((size_t)BN_ * H_ * 4);
  float* Ux   = (float*)alloc((size_t)BN_ * H_ * 4);
  float* Vx   = (float*)alloc((size_t)BN_ * H_ * 4);
  float* xtmp = (float*)alloc((size_t)BN_ * H_ * 4);
  float* sums = (float*)alloc(3 * 512 * 4);  // 3 layers x [s1E,s2E,s1N,s2N]
  float* cnts = (float*)alloc(256);
  bf16* WT    = (bf16*)alloc((size_t)4 * H_ * H_ * 2);

  hipMemsetAsync(sums, 0, 3 * 512 * 4, stream);
  k_prep_w<<<4, 256, 0, stream>>>(eUw, mUw, WT);
  k_init_x<<<BN_, 128, 0, stream>>>(coord, w_coord, x);
  k_cnt<<<1, 256, 0, stream>>>(mask, cnts);

  float* sums0 = sums;
  float* sums1 = sums + 512;
  float* sums2 = sums + 1024;

  // layer 0
  k_node_lin<0><<<BN_, 128, 0, stream>>>(
      x, xtmp, sums0, cnts, gN, bN, eVw, eVb, nUw, nUb, nVw, nVb, mask, Vxe,
      Ux, Vx);
  k_edge<0, true><<<BN_, 256, 0, stream>>>(
      e, etmp, sums0, cnts, gE, bE, x_edges, ev, w_eval, emb, WT, eUb, Vxe,
      Vx, Ux, mask, xtmp, sums0);
  // layer 1
  k_node_lin<1><<<BN_, 128, 0, stream>>>(
      x, xtmp, sums0, cnts, gN, bN, eVw + H_ * H_, eVb + H_, nUw + H_ * H_,
      nUb + H_, nVw + H_ * H_, nVb + H_, mask, Vxe, Ux, Vx);
  k_edge<2, true><<<BN_, 256, 0, stream>>>(
      e, etmp, sums0, cnts, gE, bE, x_edges, ev, w_eval, emb, WT + H_ * H_,
      eUb + H_, Vxe, Vx, Ux, mask, xtmp, sums1);
  // layer 2
  k_node_lin<1><<<BN_, 128, 0, stream>>>(
      x, xtmp, sums1, cnts, gN + H_, bN + H_, eVw + 2 * H_ * H_,
      eVb + 2 * H_, nUw + 2 * H_ * H_, nUb + 2 * H_, nVw + 2 * H_ * H_,
      nVb + 2 * H_, mask, Vxe, Ux, Vx);
  k_edge<1, false><<<BN_, 256, 0, stream>>>(
      e, etmp, sums1, cnts, gE + H_, bE + H_, x_edges, ev, w_eval, emb,
      WT + 2 * H_ * H_, eUb + 2 * H_, Vxe, Vx, Ux, mask, xtmp, sums2);
  // head
  k_head<<<BN_, 256, 0, stream>>>(e, etmp, sums2, cnts, gE + 2 * H_,
                                  bE + 2 * H_, WT + (size_t)3 * H_ * H_, mUb,
                                  mVw, mVb, mask, (float*)d_out);
}

// Round 8
// 384.593 us; speedup vs baseline: 1.6137x; 1.2286x over previous
//
#include <hip/hip_runtime.h>
#include <hip/hip_bf16.h>

// ConvTSP gated-GCN forward, MI355X (gfx950). Round 8.
// B=4, N=200, H=128, L=3. f32 in/out, x_edges int32.
//
// Unified R4-R7 post-mortem: regressions were SCRATCH SPILL traffic.
//  - R4/R5/R6: __launch_bounds__(256,8)/(256,6) capped VGPR at 64/85 while
//    the kernel needs ~100 (B-frags alone = 32 VGPR) -> forced spill ->
//    +100-200 MB HBM traffic (WRITE_SIZE mode-independent, FETCH >> logical).
//  - R7: private arrays (v[8], scr[8], tu[8], load_pre ptr args) -> scratch
//    despite VGPR headroom (rule #20).
// Round 8 = R3's proven-clean shape (named scalars, constant-index vectors,
// (256,3), no private arrays) + validated byte diet (bf16 e, no e0
// materialization) + R7's dispatch-count reduction (inline ss, fused x-upd).

typedef __hip_bfloat16 bf16;
typedef __attribute__((ext_vector_type(8))) short short8_t;
typedef __attribute__((ext_vector_type(4))) float f32x4;

#define B_ 4
#define N_ 200
#define H_ 128
#define BN_ (B_ * N_)
#define MT_ 13
#define MROWS_ 208

__device__ __forceinline__ unsigned short f2b(float f) {
  unsigned int i = __float_as_uint(f);
  i = (i + 0x7fffu + ((i >> 16) & 1u)) >> 16;  // RNE
  return (unsigned short)i;
}
__device__ __forceinline__ float b2f16(unsigned short u) {
  return __uint_as_float((unsigned int)u << 16);
}

// ---------------- init ----------------

__global__ __launch_bounds__(128) void k_init_x(
    const float* __restrict__ coord, const float* __restrict__ w_coord,
    float* __restrict__ x) {
  int bi = blockIdx.x, h = threadIdx.x;
  float c0 = coord[bi * 2 + 0], c1 = coord[bi * 2 + 1];
  x[(size_t)bi * H_ + h] = c0 * w_coord[h] + c1 * w_coord[H_ + h];
}

__global__ __launch_bounds__(256) void k_cnt(const float* __restrict__ mask,
                                             float* __restrict__ cnts) {
  int t = threadIdx.x, b = t >> 6, l = t & 63;
  float s = 0.f;
  for (int n = l; n < N_; n += 64) s += mask[b * N_ + n];
#pragma unroll
  for (int d = 1; d < 64; d <<= 1) s += __shfl_xor(s, d);
  __shared__ float ms[B_];
  if (l == 0) ms[b] = s;
  __syncthreads();
  if (t == 0) {
    float cn = 0.f, ce = 0.f;
    for (int k = 0; k < B_; ++k) { cn += ms[k]; ce += ms[k] * ms[k]; }
    cnts[0] = cn; cnts[1] = ce;
  }
}

// transpose eU_w[0..2] and mlp_U_w into [out][in] bf16
__global__ __launch_bounds__(256) void k_prep_w(const float* __restrict__ eUw,
                                                const float* __restrict__ mUw,
                                                bf16* __restrict__ WT) {
  int blk = blockIdx.x;
  const float* src = (blk < 3) ? (eUw + (size_t)blk * H_ * H_) : mUw;
  bf16* dst = WT + (size_t)blk * H_ * H_;
  for (int q = threadIdx.x; q < H_ * H_; q += 256) {
    int out = q >> 7, in = q & 127;
    dst[q] = __float2bfloat16(src[in * H_ + out]);
  }
}

// ---------------- node linears (+fused x update, inline ssN) -------------

template <int UPD>
__global__ __launch_bounds__(128) void k_node_lin(
    float* __restrict__ x, const float* __restrict__ xtmp,
    const float* __restrict__ sumsPrev, const float* __restrict__ cnts,
    const float* __restrict__ gNp, const float* __restrict__ bNp,
    const float* __restrict__ eVw, const float* __restrict__ eVb,
    const float* __restrict__ nUw, const float* __restrict__ nUb,
    const float* __restrict__ nVw, const float* __restrict__ nVb,
    const float* __restrict__ mask, float* __restrict__ Vxe,
    float* __restrict__ Ux, float* __restrict__ Vx) {
  __shared__ float xr[H_];
  int bi = blockIdx.x, h = threadIdx.x;
  float m = mask[bi];
  float xv = x[(size_t)bi * H_ + h];
  if (UPD) {
    float cntN = cnts[0];
    float mN = sumsPrev[256 + h] / cntN;
    float vN = sumsPrev[384 + h] / cntN - mN * mN;
    float scN = gNp[h] * rsqrtf(vN + 1e-5f);
    float shN = bNp[h] - mN * scN;
    float tv = xtmp[(size_t)bi * H_ + h];
    float xn = (m > 0.f) ? fmaf(tv, scN, shN) : tv;
    xv += fmaxf(xn, 0.f);
    x[(size_t)bi * H_ + h] = xv;
  }
  xr[h] = xv;
  __syncthreads();
  float a = 0.f, bvv = 0.f, c = 0.f;
#pragma unroll 4
  for (int k = 0; k < H_; ++k) {
    float kx = xr[k];
    a   = fmaf(kx, eVw[k * H_ + h], a);
    bvv = fmaf(kx, nUw[k * H_ + h], bvv);
    c   = fmaf(kx, nVw[k * H_ + h], c);
  }
  Vxe[(size_t)bi * H_ + h] = m * (a + eVb[h]);
  Ux[(size_t)bi * H_ + h]  = m * (bvv + nUb[h]);
  Vx[(size_t)bi * H_ + h]  = m * (c + nVb[h]);
}

// ---------------- big kernel: staged-update + GEMM + epilogue ------------
// MODE 0: layer 0. A = e0 from raw inputs. No e write.
// MODE 2: layer 1. A = e0(recomputed) + relu(bnE(etmp)). Writes e (bf16).
// MODE 1: layer 2. A = e + relu(bnE(etmp)); e updated in place.

template <int MODE, bool DO_X>
__global__ __launch_bounds__(256, 3) void k_edge(
    bf16* __restrict__ e, bf16* __restrict__ etmp,
    const float* __restrict__ sumsPrev, const float* __restrict__ cnts,
    const float* __restrict__ gEp, const float* __restrict__ bEp,
    const int* __restrict__ xe, const float* __restrict__ ev,
    const float* __restrict__ w_eval, const float* __restrict__ emb,
    const bf16* __restrict__ WT, const float* __restrict__ eUb,
    const float* __restrict__ Vxe, const float* __restrict__ Vx,
    const float* __restrict__ Ux, const float* __restrict__ mask,
    float* __restrict__ xtmp, float* __restrict__ sumsCur) {
  __shared__ __align__(16) char sA[MROWS_ * 256];
  __shared__ float ssE_s[256];
  const int bi = blockIdx.x;
  const int b = bi / N_;
  const int t = threadIdx.x;
  const int lane = t & 63;
  const int w = t >> 6;
  const float mask_i = mask[bi];

  // inline ssE from previous layer's sums (L2-hot, 2KB)
  if (MODE != 0) {
    int h = t & 127;
    float cntE = cnts[1];
    float mE = sumsPrev[h] / cntE;
    float vE = sumsPrev[128 + h] / cntE - mE * mE;
    float scE = gEp[h] * rsqrtf(vE + 1e-5f);
    ssE_s[t] = (t < 128) ? scE : (bEp[h] - mE * scE);
    __syncthreads();
  }

  // --- B fragments: named, no arrays ---
  const int colA = (w << 5) + (lane & 15);
  const int colB = colA + 16;
  const int kgrp = (lane >> 4) << 3;
  const short* wp0 = (const short*)WT + colA * H_ + kgrp;
  const short* wp1 = (const short*)WT + colB * H_ + kgrp;
  short8_t bfA0 = *(const short8_t*)(wp0);
  short8_t bfA1 = *(const short8_t*)(wp0 + 32);
  short8_t bfA2 = *(const short8_t*)(wp0 + 64);
  short8_t bfA3 = *(const short8_t*)(wp0 + 96);
  short8_t bfB0 = *(const short8_t*)(wp1);
  short8_t bfB1 = *(const short8_t*)(wp1 + 32);
  short8_t bfB2 = *(const short8_t*)(wp1 + 64);
  short8_t bfB3 = *(const short8_t*)(wp1 + 96);

  // --- staging: R3 shape, 8B granule, named scalars only ---
  {
    unsigned short* eb = (unsigned short*)e + (size_t)bi * N_ * H_;
    const unsigned short* tb =
        (const unsigned short*)etmp + (size_t)bi * N_ * H_;
    for (int q4 = t; q4 < MROWS_ * 32; q4 += 256) {
      int row = q4 >> 5, k0 = (q4 & 31) << 2;
      float v0 = 0.f, v1 = 0.f, v2 = 0.f, v3 = 0.f;
      if (row < N_) {
        if (MODE == 0 || MODE == 2) {
          if (k0 < 64) {
            float evv = ev[bi * N_ + row];
            float4 we = *(const float4*)(w_eval + k0);
            v0 = evv * we.x; v1 = evv * we.y;
            v2 = evv * we.z; v3 = evv * we.w;
          } else {
            float4 em4 = *(const float4*)(emb + xe[bi * N_ + row] * 64 + (k0 - 64));
            v0 = em4.x; v1 = em4.y; v2 = em4.z; v3 = em4.w;
          }
        } else {
          ushort4 e4 = *(const ushort4*)(eb + row * H_ + k0);
          v0 = b2f16(e4.x); v1 = b2f16(e4.y);
          v2 = b2f16(e4.z); v3 = b2f16(e4.w);
        }
        if (MODE != 0) {
          ushort4 t4 = *(const ushort4*)(tb + row * H_ + k0);
          float mj = mask[b * N_ + row];
          bool msk = (mask_i * mj) > 0.f;
          float sc0 = ssE_s[k0 + 0], sc1 = ssE_s[k0 + 1];
          float sc2 = ssE_s[k0 + 2], sc3 = ssE_s[k0 + 3];
          float sh0 = ssE_s[128 + k0 + 0], sh1 = ssE_s[128 + k0 + 1];
          float sh2 = ssE_s[128 + k0 + 2], sh3 = ssE_s[128 + k0 + 3];
          float f0 = b2f16(t4.x), f1 = b2f16(t4.y);
          float f2 = b2f16(t4.z), f3 = b2f16(t4.w);
          v0 += fmaxf(msk ? fmaf(f0, sc0, sh0) : f0, 0.f);
          v1 += fmaxf(msk ? fmaf(f1, sc1, sh1) : f1, 0.f);
          v2 += fmaxf(msk ? fmaf(f2, sc2, sh2) : f2, 0.f);
          v3 += fmaxf(msk ? fmaf(f3, sc3, sh3) : f3, 0.f);
        }
      }
      unsigned int p0 = ((unsigned int)f2b(v1) << 16) | f2b(v0);
      unsigned int p1 = ((unsigned int)f2b(v3) << 16) | f2b(v2);
      if (MODE != 0 && row < N_)
        *(uint2*)(eb + row * H_ + k0) = make_uint2(p0, p1);  // persist e_l
      unsigned long long pk = ((unsigned long long)p1 << 32) | p0;
      int byo = (row << 8) + ((k0 * 2) ^ ((row & 7) << 4));
      *(unsigned long long*)(sA + byo) = pk;
    }
  }
  __syncthreads();

  // --- GEMM + gate/agg/BN epilogue (R3 shape, no arrays) ---
  const float add0 = eUb[colA] + Vxe[(size_t)bi * H_ + colA];
  const float add1 = eUb[colB] + Vxe[(size_t)bi * H_ + colB];
  const float* VxeB = Vxe + (size_t)b * N_ * H_;
  const float* VxB  = Vx  + (size_t)b * N_ * H_;

  float agg0 = 0.f, agg1 = 0.f, den0 = 0.f, den1 = 0.f;
  float s1a = 0.f, s1b = 0.f, s2a = 0.f, s2b = 0.f;
  const int kb = (lane >> 4) << 4;

  for (int mt = 0; mt < MT_; ++mt) {
    f32x4 acc0 = {0.f, 0.f, 0.f, 0.f}, acc1 = {0.f, 0.f, 0.f, 0.f};
    int ra = (mt << 4) + (lane & 15);
    const char* ap = sA + (ra << 8);
    int sw = (ra & 7) << 4;
    short8_t av;
    av = *(const short8_t*)(ap + ((kb + 0) ^ sw));
    acc0 = __builtin_amdgcn_mfma_f32_16x16x32_bf16(av, bfA0, acc0, 0, 0, 0);
    acc1 = __builtin_amdgcn_mfma_f32_16x16x32_bf16(av, bfB0, acc1, 0, 0, 0);
    av = *(const short8_t*)(ap + ((kb + 64) ^ sw));
    acc0 = __builtin_amdgcn_mfma_f32_16x16x32_bf16(av, bfA1, acc0, 0, 0, 0);
    acc1 = __builtin_amdgcn_mfma_f32_16x16x32_bf16(av, bfB1, acc1, 0, 0, 0);
    av = *(const short8_t*)(ap + ((kb + 128) ^ sw));
    acc0 = __builtin_amdgcn_mfma_f32_16x16x32_bf16(av, bfA2, acc0, 0, 0, 0);
    acc1 = __builtin_amdgcn_mfma_f32_16x16x32_bf16(av, bfB2, acc1, 0, 0, 0);
    av = *(const short8_t*)(ap + ((kb + 192) ^ sw));
    acc0 = __builtin_amdgcn_mfma_f32_16x16x32_bf16(av, bfA3, acc0, 0, 0, 0);
    acc1 = __builtin_amdgcn_mfma_f32_16x16x32_bf16(av, bfB3, acc1, 0, 0, 0);
#pragma unroll
    for (int r = 0; r < 4; ++r) {
      int j = (mt << 4) + ((lane >> 4) << 2) + r;
      bool valid = (j < N_);
      float mj = valid ? mask[b * N_ + j] : 0.f;
      float sqm = mask_i * mj;
      float vj0 = valid ? VxeB[(size_t)j * H_ + colA] : 0.f;
      float vj1 = valid ? VxeB[(size_t)j * H_ + colB] : 0.f;
      float t0 = acc0[r] + add0 + vj0;
      float t1 = acc1[r] + add1 + vj1;
      if (valid) {
        size_t o = ((size_t)bi * N_ + j) * H_;
        ((unsigned short*)etmp)[o + colA] = f2b(t0);
        ((unsigned short*)etmp)[o + colB] = f2b(t1);
      }
      float g0 = sqm / (1.f + __expf(-t0));
      float g1 = sqm / (1.f + __expf(-t1));
      float vx0 = valid ? VxB[(size_t)j * H_ + colA] : 0.f;
      float vx1 = valid ? VxB[(size_t)j * H_ + colB] : 0.f;
      agg0 = fmaf(g0, vx0, agg0);
      agg1 = fmaf(g1, vx1, agg1);
      den0 += g0; den1 += g1;
      s1a = fmaf(t0, sqm, s1a);
      s1b = fmaf(t1, sqm, s1b);
      s2a = fmaf(t0 * sqm, t0, s2a);
      s2b = fmaf(t1 * sqm, t1, s2b);
    }
  }
#pragma unroll
  for (int d = 16; d <= 32; d <<= 1) {
    agg0 += __shfl_xor(agg0, d); agg1 += __shfl_xor(agg1, d);
    den0 += __shfl_xor(den0, d); den1 += __shfl_xor(den1, d);
    s1a += __shfl_xor(s1a, d);   s1b += __shfl_xor(s1b, d);
    s2a += __shfl_xor(s2a, d);   s2b += __shfl_xor(s2b, d);
  }
  if ((lane >> 4) == 0) {
    atomicAdd(&sumsCur[colA], s1a);
    atomicAdd(&sumsCur[colB], s1b);
    atomicAdd(&sumsCur[128 + colA], s2a);
    atomicAdd(&sumsCur[128 + colB], s2b);
    if (DO_X) {
      float xt0 = Ux[(size_t)bi * H_ + colA] + agg0 / (1e-20f + den0);
      float xt1 = Ux[(size_t)bi * H_ + colB] + agg1 / (1e-20f + den1);
      xtmp[(size_t)bi * H_ + colA] = xt0;
      xtmp[(size_t)bi * H_ + colB] = xt1;
      atomicAdd(&sumsCur[256 + colA], xt0 * mask_i);
      atomicAdd(&sumsCur[384 + colA], xt0 * xt0 * mask_i);
      atomicAdd(&sumsCur[256 + colB], xt1 * mask_i);
      atomicAdd(&sumsCur[384 + colB], xt1 * xt1 * mask_i);
    }
  }
}

// ---------------- head: A = e + relu(bnE(etmp)); y = relu(A@U+bU)@V + bV --

__global__ __launch_bounds__(256, 2) void k_head(
    const bf16* __restrict__ e, const bf16* __restrict__ etmp,
    const float* __restrict__ sumsPrev, const float* __restrict__ cnts,
    const float* __restrict__ gEp, const float* __restrict__ bEp,
    const bf16* __restrict__ UT, const float* __restrict__ Ub,
    const float* __restrict__ Vw, const float* __restrict__ Vb,
    const float* __restrict__ mask, float* __restrict__ y) {
  __shared__ __align__(16) char sA[MROWS_ * 256];
  __shared__ float part[4][MROWS_][2];
  __shared__ float ssE_s[256];
  const int bi = blockIdx.x;
  const int b = bi / N_;
  const int t = threadIdx.x;
  const int lane = t & 63;
  const int w = t >> 6;
  const float mask_i = mask[bi];

  {
    int h = t & 127;
    float cntE = cnts[1];
    float mE = sumsPrev[h] / cntE;
    float vE = sumsPrev[128 + h] / cntE - mE * mE;
    float scE = gEp[h] * rsqrtf(vE + 1e-5f);
    ssE_s[t] = (t < 128) ? scE : (bEp[h] - mE * scE);
    __syncthreads();
  }

  const int colA = (w << 5) + (lane & 15);
  const int colB = colA + 16;
  const int kgrp = (lane >> 4) << 3;
  const short* wp0 = (const short*)UT + colA * H_ + kgrp;
  const short* wp1 = (const short*)UT + colB * H_ + kgrp;
  short8_t bfA0 = *(const short8_t*)(wp0);
  short8_t bfA1 = *(const short8_t*)(wp0 + 32);
  short8_t bfA2 = *(const short8_t*)(wp0 + 64);
  short8_t bfA3 = *(const short8_t*)(wp0 + 96);
  short8_t bfB0 = *(const short8_t*)(wp1);
  short8_t bfB1 = *(const short8_t*)(wp1 + 32);
  short8_t bfB2 = *(const short8_t*)(wp1 + 64);
  short8_t bfB3 = *(const short8_t*)(wp1 + 96);

  {
    const unsigned short* eb = (const unsigned short*)e + (size_t)bi * N_ * H_;
    const unsigned short* tb =
        (const unsigned short*)etmp + (size_t)bi * N_ * H_;
    for (int q4 = t; q4 < MROWS_ * 32; q4 += 256) {
      int row = q4 >> 5, k0 = (q4 & 31) << 2;
      float v0 = 0.f, v1 = 0.f, v2 = 0.f, v3 = 0.f;
      if (row < N_) {
        ushort4 e4 = *(const ushort4*)(eb + row * H_ + k0);
        ushort4 t4 = *(const ushort4*)(tb + row * H_ + k0);
        float mj = mask[b * N_ + row];
        bool msk = (mask_i * mj) > 0.f;
        float sc0 = ssE_s[k0 + 0], sc1 = ssE_s[k0 + 1];
        float sc2 = ssE_s[k0 + 2], sc3 = ssE_s[k0 + 3];
        float sh0 = ssE_s[128 + k0 + 0], sh1 = ssE_s[128 + k0 + 1];
        float sh2 = ssE_s[128 + k0 + 2], sh3 = ssE_s[128 + k0 + 3];
        float f0 = b2f16(t4.x), f1 = b2f16(t4.y);
        float f2 = b2f16(t4.z), f3 = b2f16(t4.w);
        v0 = b2f16(e4.x) + fmaxf(msk ? fmaf(f0, sc0, sh0) : f0, 0.f);
        v1 = b2f16(e4.y) + fmaxf(msk ? fmaf(f1, sc1, sh1) : f1, 0.f);
        v2 = b2f16(e4.z) + fmaxf(msk ? fmaf(f2, sc2, sh2) : f2, 0.f);
        v3 = b2f16(e4.w) + fmaxf(msk ? fmaf(f3, sc3, sh3) : f3, 0.f);
      }
      unsigned int p0 = ((unsigned int)f2b(v1) << 16) | f2b(v0);
      unsigned int p1 = ((unsigned int)f2b(v3) << 16) | f2b(v2);
      unsigned long long pk = ((unsigned long long)p1 << 32) | p0;
      int byo = (row << 8) + ((k0 * 2) ^ ((row & 7) << 4));
      *(unsigned long long*)(sA + byo) = pk;
    }
  }
  __syncthreads();

  float bu0 = Ub[colA], bu1 = Ub[colB];
  float v00 = Vw[colA * 2], v01 = Vw[colA * 2 + 1];
  float v10 = Vw[colB * 2], v11 = Vw[colB * 2 + 1];
  const int kb = (lane >> 4) << 4;

  for (int mt = 0; mt < MT_; ++mt) {
    f32x4 acc0 = {0.f, 0.f, 0.f, 0.f}, acc1 = {0.f, 0.f, 0.f, 0.f};
    int ra = (mt << 4) + (lane & 15);
    const char* ap = sA + (ra << 8);
    int sw = (ra & 7) << 4;
    short8_t av;
    av = *(const short8_t*)(ap + ((kb + 0) ^ sw));
    acc0 = __builtin_amdgcn_mfma_f32_16x16x32_bf16(av, bfA0, acc0, 0, 0, 0);
    acc1 = __builtin_amdgcn_mfma_f32_16x16x32_bf16(av, bfB0, acc1, 0, 0, 0);
    av = *(const short8_t*)(ap + ((kb + 64) ^ sw));
    acc0 = __builtin_amdgcn_mfma_f32_16x16x32_bf16(av, bfA1, acc0, 0, 0, 0);
    acc1 = __builtin_amdgcn_mfma_f32_16x16x32_bf16(av, bfB1, acc1, 0, 0, 0);
    av = *(const short8_t*)(ap + ((kb + 128) ^ sw));
    acc0 = __builtin_amdgcn_mfma_f32_16x16x32_bf16(av, bfA2, acc0, 0, 0, 0);
    acc1 = __builtin_amdgcn_mfma_f32_16x16x32_bf16(av, bfB2, acc1, 0, 0, 0);
    av = *(const short8_t*)(ap + ((kb + 192) ^ sw));
    acc0 = __builtin_amdgcn_mfma_f32_16x16x32_bf16(av, bfA3, acc0, 0, 0, 0);
    acc1 = __builtin_amdgcn_mfma_f32_16x16x32_bf16(av, bfB3, acc1, 0, 0, 0);
#pragma unroll
    for (int r = 0; r < 4; ++r) {
      float h0v = fmaxf(acc0[r] + bu0, 0.f);
      float h1v = fmaxf(acc1[r] + bu1, 0.f);
      float p0 = h0v * v00 + h1v * v10;
      float p1 = h0v * v01 + h1v * v11;
#pragma unroll
      for (int d = 1; d < 16; d <<= 1) {
        p0 += __shfl_xor(p0, d);
        p1 += __shfl_xor(p1, d);
      }
      int jl = (mt << 4) + ((lane >> 4) << 2) + r;
      if ((lane & 15) == 0) { part[w][jl][0] = p0; part[w][jl][1] = p1; }
    }
  }
  __syncthreads();
  float vb0 = Vb[0], vb1 = Vb[1];
  for (int q = t; q < N_ * 2; q += 256) {
    int j = q >> 1, c = q & 1;
    float s = part[0][j][c] + part[1][j][c] + part[2][j][c] + part[3][j][c] +
              (c ? vb1 : vb0);
    y[((size_t)bi * N_ + j) * 2 + c] = s;
  }
}

// ---------------- launch ----------------

extern "C" void kernel_launch(void* const* d_in, const int* in_sizes, int n_in,
                              void* d_out, int out_size, void* d_ws,
                              size_t ws_size, hipStream_t stream) {
  const int*   x_edges = (const int*)d_in[0];
  const float* ev      = (const float*)d_in[1];
  const float* coord   = (const float*)d_in[2];
  const float* mask    = (const float*)d_in[3];
  const float* w_coord = (const float*)d_in[4];
  const float* w_eval  = (const float*)d_in[5];
  const float* emb     = (const float*)d_in[6];
  const float* eUw = (const float*)d_in[7];
  const float* eUb = (const float*)d_in[8];
  const float* eVw = (const float*)d_in[9];
  const float* eVb = (const float*)d_in[10];
  const float* nUw = (const float*)d_in[11];
  const float* nUb = (const float*)d_in[12];
  const float* nVw = (const float*)d_in[13];
  const float* nVb = (const float*)d_in[14];
  const float* gE  = (const float*)d_in[15];
  const float* bE  = (const float*)d_in[16];
  const float* gN  = (const float*)d_in[17];
  const float* bN  = (const float*)d_in[18];
  const float* mUw = (const float*)d_in[19];
  const float* mUb = (const float*)d_in[20];
  const float* mVw = (const float*)d_in[21];
  const float* mVb = (const float*)d_in[22];

  char* ws = (char*)d_ws;
  size_t off = 0;
  auto alloc = [&](size_t bytes) {
    void* p = ws + off;
    off += (bytes + 255) & ~(size_t)255;
    return p;
  };
  bf16* e     = (bf16*)alloc((size_t)B_ * N_ * N_ * H_ * 2);   // 40.96 MB
  bf16* etmp  = (bf16*)alloc((size_t)B_ * N_ * N_ * H_ * 2);   // 40.96 MB
  float* x    = (float*)alloc((size_t)BN_ * H_ * 4);
  float* Vxe  = (float*)alloc((size_t)BN_ * H_ * 4);
  float* Ux   = (float*)alloc((size_t)BN_ * H_ * 4);
  float* Vx   = (float*)alloc((size_t)BN_ * H_ * 4);
  float* xtmp = (float*)alloc((size_t)BN_ * H_ * 4);
  float* sums = (float*)alloc(3 * 512 * 4);  // 3 layers x [s1E,s2E,s1N,s2N]
  float* cnts = (float*)alloc(256);
  bf16* WT    = (bf16*)alloc((size_t)4 * H_ * H_ * 2);

  hipMemsetAsync(sums, 0, 3 * 512 * 4, stream);
  k_prep_w<<<4, 256, 0, stream>>>(eUw, mUw, WT);
  k_init_x<<<BN_, 128, 0, stream>>>(coord, w_coord, x);
  k_cnt<<<1, 256, 0, stream>>>(mask, cnts);

  float* sums0 = sums;
  float* sums1 = sums + 512;
  float* sums2 = sums + 1024;

  // layer 0
  k_node_lin<0><<<BN_, 128, 0, stream>>>(
      x, xtmp, sums0, cnts, gN, bN, eVw, eVb, nUw, nUb, nVw, nVb, mask, Vxe,
      Ux, Vx);
  k_edge<0, true><<<BN_, 256, 0, stream>>>(
      e, etmp, sums0, cnts, gE, bE, x_edges, ev, w_eval, emb, WT, eUb, Vxe,
      Vx, Ux, mask, xtmp, sums0);
  // layer 1
  k_node_lin<1><<<BN_, 128, 0, stream>>>(
      x, xtmp, sums0, cnts, gN, bN, eVw + H_ * H_, eVb + H_, nUw + H_ * H_,
      nUb + H_, nVw + H_ * H_, nVb + H_, mask, Vxe, Ux, Vx);
  k_edge<2, true><<<BN_, 256, 0, stream>>>(
      e, etmp, sums0, cnts, gE, bE, x_edges, ev, w_eval, emb, WT + H_ * H_,
      eUb + H_, Vxe, Vx, Ux, mask, xtmp, sums1);
  // layer 2
  k_node_lin<1><<<BN_, 128, 0, stream>>>(
      x, xtmp, sums1, cnts, gN + H_, bN + H_, eVw + 2 * H_ * H_,
      eVb + 2 * H_, nUw + 2 * H_ * H_, nUb + 2 * H_, nVw + 2 * H_ * H_,
      nVb + 2 * H_, mask, Vxe, Ux, Vx);
  k_edge<1, false><<<BN_, 256, 0, stream>>>(
      e, etmp, sums1, cnts, gE + H_, bE + H_, x_edges, ev, w_eval, emb,
      WT + 2 * H_ * H_, eUb + 2 * H_, Vxe, Vx, Ux, mask, xtmp, sums2);
  // head
  k_head<<<BN_, 256, 0, stream>>>(e, etmp, sums2, cnts, gE + 2 * H_,
                                  bE + 2 * H_, WT + (size_t)3 * H_ * H_, mUb,
                                  mVw, mVb, mask, (float*)d_out);
}

// Round 9
// 346.648 us; speedup vs baseline: 1.7904x; 1.1095x over previous
//
#include <hip/hip_runtime.h>
#include <hip/hip_bf16.h>

// ConvTSP gated-GCN forward, MI355X (gfx950). Round 9.
// B=4, N=200, H=128, L=3. f32 in/out, x_edges int32.
//
// R8 post-mortem: bytes now clean (82 MB write = logical), but k_edge is
// latency-bound: 0.96 TB/s, 16% occupancy, 800 blocks = 3.1/CU + tail.
// R4-R6's "j-split inflates bytes" was spill artifact (VGPR 32-40 caps);
// never tested spill-free. Round 9 = R8's exact clean code shape
// (named scalars, no arrays, (256,3)) + j-split x4 (grid 3200, LDS 16.4KB)
// + R5's contention-free partial reductions (pS/pAgg/pDen + k_xfin/k_red).

typedef __hip_bfloat16 bf16;
typedef __attribute__((ext_vector_type(8))) short short8_t;
typedef __attribute__((ext_vector_type(4))) float f32x4;

#define B_ 4
#define N_ 200
#define H_ 128
#define BN_ (B_ * N_)
#define JT_ 4
#define NBLK_ (BN_ * JT_)
#define MAXROWS_ 64

__device__ __forceinline__ unsigned short f2b(float f) {
  unsigned int i = __float_as_uint(f);
  i = (i + 0x7fffu + ((i >> 16) & 1u)) >> 16;  // RNE
  return (unsigned short)i;
}
__device__ __forceinline__ float b2f16(unsigned short u) {
  return __uint_as_float((unsigned int)u << 16);
}

// ---------------- init ----------------

__global__ __launch_bounds__(128) void k_init_x(
    const float* __restrict__ coord, const float* __restrict__ w_coord,
    float* __restrict__ x) {
  int bi = blockIdx.x, h = threadIdx.x;
  float c0 = coord[bi * 2 + 0], c1 = coord[bi * 2 + 1];
  x[(size_t)bi * H_ + h] = c0 * w_coord[h] + c1 * w_coord[H_ + h];
}

__global__ __launch_bounds__(256) void k_cnt(const float* __restrict__ mask,
                                             float* __restrict__ cnts) {
  int t = threadIdx.x, b = t >> 6, l = t & 63;
  float s = 0.f;
  for (int n = l; n < N_; n += 64) s += mask[b * N_ + n];
#pragma unroll
  for (int d = 1; d < 64; d <<= 1) s += __shfl_xor(s, d);
  __shared__ float ms[B_];
  if (l == 0) ms[b] = s;
  __syncthreads();
  if (t == 0) {
    float cn = 0.f, ce = 0.f;
    for (int k = 0; k < B_; ++k) { cn += ms[k]; ce += ms[k] * ms[k]; }
    cnts[0] = cn; cnts[1] = ce;
  }
}

// transpose eU_w[0..2] and mlp_U_w into [out][in] bf16
__global__ __launch_bounds__(256) void k_prep_w(const float* __restrict__ eUw,
                                                const float* __restrict__ mUw,
                                                bf16* __restrict__ WT) {
  int blk = blockIdx.x;
  const float* src = (blk < 3) ? (eUw + (size_t)blk * H_ * H_) : mUw;
  bf16* dst = WT + (size_t)blk * H_ * H_;
  for (int q = threadIdx.x; q < H_ * H_; q += 256) {
    int out = q >> 7, in = q & 127;
    dst[q] = __float2bfloat16(src[in * H_ + out]);
  }
}

// ---------------- node linears (+fused x update, inline ssN) -------------

template <int UPD>
__global__ __launch_bounds__(128) void k_node_lin(
    float* __restrict__ x, const float* __restrict__ xtmp,
    const float* __restrict__ sumsPrev, const float* __restrict__ cnts,
    const float* __restrict__ gNp, const float* __restrict__ bNp,
    const float* __restrict__ eVw, const float* __restrict__ eVb,
    const float* __restrict__ nUw, const float* __restrict__ nUb,
    const float* __restrict__ nVw, const float* __restrict__ nVb,
    const float* __restrict__ mask, float* __restrict__ Vxe,
    float* __restrict__ Ux, float* __restrict__ Vx) {
  __shared__ float xr[H_];
  int bi = blockIdx.x, h = threadIdx.x;
  float m = mask[bi];
  float xv = x[(size_t)bi * H_ + h];
  if (UPD) {
    float cntN = cnts[0];
    float mN = sumsPrev[256 + h] / cntN;
    float vN = sumsPrev[384 + h] / cntN - mN * mN;
    float scN = gNp[h] * rsqrtf(vN + 1e-5f);
    float shN = bNp[h] - mN * scN;
    float tv = xtmp[(size_t)bi * H_ + h];
    float xn = (m > 0.f) ? fmaf(tv, scN, shN) : tv;
    xv += fmaxf(xn, 0.f);
    x[(size_t)bi * H_ + h] = xv;
  }
  xr[h] = xv;
  __syncthreads();
  float a = 0.f, bvv = 0.f, c = 0.f;
#pragma unroll 4
  for (int k = 0; k < H_; ++k) {
    float kx = xr[k];
    a   = fmaf(kx, eVw[k * H_ + h], a);
    bvv = fmaf(kx, nUw[k * H_ + h], bvv);
    c   = fmaf(kx, nVw[k * H_ + h], c);
  }
  Vxe[(size_t)bi * H_ + h] = m * (a + eVb[h]);
  Ux[(size_t)bi * H_ + h]  = m * (bvv + nUb[h]);
  Vx[(size_t)bi * H_ + h]  = m * (c + nVb[h]);
}

// ---------------- big kernel: staged-update + GEMM + epilogue ------------
// grid = BN_*JT_. blockIdx -> (bi, jh). Block owns j-tiles [mt0,mt1).
// MODE 0: layer 0. A = e0 from raw inputs. No e write.
// MODE 2: layer 1. A = e0(recomputed) + relu(bnE(etmp)). Writes e (bf16).
// MODE 1: layer 2. A = e + relu(bnE(etmp)); e updated in place.
// NO global atomics: per-block partials to pS / pAgg / pDen.

template <int MODE, bool DO_X>
__global__ __launch_bounds__(256, 3) void k_edge(
    bf16* __restrict__ e, bf16* __restrict__ etmp,
    const float* __restrict__ sumsPrev, const float* __restrict__ cnts,
    const float* __restrict__ gEp, const float* __restrict__ bEp,
    const int* __restrict__ xe, const float* __restrict__ ev,
    const float* __restrict__ w_eval, const float* __restrict__ emb,
    const bf16* __restrict__ WT, const float* __restrict__ eUb,
    const float* __restrict__ Vxe, const float* __restrict__ Vx,
    const float* __restrict__ mask, float* __restrict__ pS,
    float* __restrict__ pAgg, float* __restrict__ pDen) {
  __shared__ __align__(16) char sA[MAXROWS_ * 256];
  __shared__ float ssE_s[256];
  const int bi = blockIdx.x >> 2;
  const int jh = blockIdx.x & 3;
  const int mt0 = (jh == 0) ? 0 : 3 * jh + 1;
  const int mt1 = 3 * jh + 4;
  const int b = bi / N_;
  const int t = threadIdx.x;
  const int lane = t & 63;
  const int w = t >> 6;
  const float mask_i = mask[bi];

  // inline ssE from previous layer's sums (L2-hot, 2KB)
  if (MODE != 0) {
    int h = t & 127;
    float cntE = cnts[1];
    float mE = sumsPrev[h] / cntE;
    float vE = sumsPrev[128 + h] / cntE - mE * mE;
    float scE = gEp[h] * rsqrtf(vE + 1e-5f);
    ssE_s[t] = (t < 128) ? scE : (bEp[h] - mE * scE);
    __syncthreads();
  }

  // --- B fragments: named, no arrays ---
  const int colA = (w << 5) + (lane & 15);
  const int colB = colA + 16;
  const int kgrp = (lane >> 4) << 3;
  const short* wp0 = (const short*)WT + colA * H_ + kgrp;
  const short* wp1 = (const short*)WT + colB * H_ + kgrp;
  short8_t bfA0 = *(const short8_t*)(wp0);
  short8_t bfA1 = *(const short8_t*)(wp0 + 32);
  short8_t bfA2 = *(const short8_t*)(wp0 + 64);
  short8_t bfA3 = *(const short8_t*)(wp0 + 96);
  short8_t bfB0 = *(const short8_t*)(wp1);
  short8_t bfB1 = *(const short8_t*)(wp1 + 32);
  short8_t bfB2 = *(const short8_t*)(wp1 + 64);
  short8_t bfB3 = *(const short8_t*)(wp1 + 96);

  // --- staging: rows [mt0*16, mt1*16), 8B granule, named scalars ---
  {
    const int nrt = (mt1 - mt0) << 4;  // 48 or 64 rows
    unsigned short* eb = (unsigned short*)e + (size_t)bi * N_ * H_;
    const unsigned short* tb =
        (const unsigned short*)etmp + (size_t)bi * N_ * H_;
    for (int q4 = t; q4 < nrt * 32; q4 += 256) {
      int lr = q4 >> 5, k0 = (q4 & 31) << 2;
      int row = (mt0 << 4) + lr;
      float v0 = 0.f, v1 = 0.f, v2 = 0.f, v3 = 0.f;
      if (row < N_) {
        if (MODE == 0 || MODE == 2) {
          if (k0 < 64) {
            float evv = ev[bi * N_ + row];
            float4 we = *(const float4*)(w_eval + k0);
            v0 = evv * we.x; v1 = evv * we.y;
            v2 = evv * we.z; v3 = evv * we.w;
          } else {
            float4 em4 = *(const float4*)(emb + xe[bi * N_ + row] * 64 + (k0 - 64));
            v0 = em4.x; v1 = em4.y; v2 = em4.z; v3 = em4.w;
          }
        } else {
          ushort4 e4 = *(const ushort4*)(eb + row * H_ + k0);
          v0 = b2f16(e4.x); v1 = b2f16(e4.y);
          v2 = b2f16(e4.z); v3 = b2f16(e4.w);
        }
        if (MODE != 0) {
          ushort4 t4 = *(const ushort4*)(tb + row * H_ + k0);
          float mj = mask[b * N_ + row];
          bool msk = (mask_i * mj) > 0.f;
          float sc0 = ssE_s[k0 + 0], sc1 = ssE_s[k0 + 1];
          float sc2 = ssE_s[k0 + 2], sc3 = ssE_s[k0 + 3];
          float sh0 = ssE_s[128 + k0 + 0], sh1 = ssE_s[128 + k0 + 1];
          float sh2 = ssE_s[128 + k0 + 2], sh3 = ssE_s[128 + k0 + 3];
          float f0 = b2f16(t4.x), f1 = b2f16(t4.y);
          float f2 = b2f16(t4.z), f3 = b2f16(t4.w);
          v0 += fmaxf(msk ? fmaf(f0, sc0, sh0) : f0, 0.f);
          v1 += fmaxf(msk ? fmaf(f1, sc1, sh1) : f1, 0.f);
          v2 += fmaxf(msk ? fmaf(f2, sc2, sh2) : f2, 0.f);
          v3 += fmaxf(msk ? fmaf(f3, sc3, sh3) : f3, 0.f);
        }
      }
      unsigned int p0 = ((unsigned int)f2b(v1) << 16) | f2b(v0);
      unsigned int p1 = ((unsigned int)f2b(v3) << 16) | f2b(v2);
      if (MODE != 0 && row < N_)
        *(uint2*)(eb + row * H_ + k0) = make_uint2(p0, p1);  // persist e_l
      unsigned long long pk = ((unsigned long long)p1 << 32) | p0;
      int byo = (lr << 8) + ((k0 * 2) ^ ((lr & 7) << 4));
      *(unsigned long long*)(sA + byo) = pk;
    }
  }
  __syncthreads();

  // --- GEMM + gate/agg/BN epilogue (R8 shape, no arrays) ---
  const float add0 = eUb[colA] + Vxe[(size_t)bi * H_ + colA];
  const float add1 = eUb[colB] + Vxe[(size_t)bi * H_ + colB];
  const float* VxeB = Vxe + (size_t)b * N_ * H_;
  const float* VxB  = Vx  + (size_t)b * N_ * H_;

  float agg0 = 0.f, agg1 = 0.f, den0 = 0.f, den1 = 0.f;
  float s1a = 0.f, s1b = 0.f, s2a = 0.f, s2b = 0.f;
  const int kb = (lane >> 4) << 4;

  for (int mt = mt0; mt < mt1; ++mt) {
    f32x4 acc0 = {0.f, 0.f, 0.f, 0.f}, acc1 = {0.f, 0.f, 0.f, 0.f};
    int ra = ((mt - mt0) << 4) + (lane & 15);
    const char* ap = sA + (ra << 8);
    int sw = (ra & 7) << 4;
    short8_t av;
    av = *(const short8_t*)(ap + ((kb + 0) ^ sw));
    acc0 = __builtin_amdgcn_mfma_f32_16x16x32_bf16(av, bfA0, acc0, 0, 0, 0);
    acc1 = __builtin_amdgcn_mfma_f32_16x16x32_bf16(av, bfB0, acc1, 0, 0, 0);
    av = *(const short8_t*)(ap + ((kb + 64) ^ sw));
    acc0 = __builtin_amdgcn_mfma_f32_16x16x32_bf16(av, bfA1, acc0, 0, 0, 0);
    acc1 = __builtin_amdgcn_mfma_f32_16x16x32_bf16(av, bfB1, acc1, 0, 0, 0);
    av = *(const short8_t*)(ap + ((kb + 128) ^ sw));
    acc0 = __builtin_amdgcn_mfma_f32_16x16x32_bf16(av, bfA2, acc0, 0, 0, 0);
    acc1 = __builtin_amdgcn_mfma_f32_16x16x32_bf16(av, bfB2, acc1, 0, 0, 0);
    av = *(const short8_t*)(ap + ((kb + 192) ^ sw));
    acc0 = __builtin_amdgcn_mfma_f32_16x16x32_bf16(av, bfA3, acc0, 0, 0, 0);
    acc1 = __builtin_amdgcn_mfma_f32_16x16x32_bf16(av, bfB3, acc1, 0, 0, 0);
#pragma unroll
    for (int r = 0; r < 4; ++r) {
      int j = (mt << 4) + ((lane >> 4) << 2) + r;
      bool valid = (j < N_);
      float mj = valid ? mask[b * N_ + j] : 0.f;
      float sqm = mask_i * mj;
      float vj0 = valid ? VxeB[(size_t)j * H_ + colA] : 0.f;
      float vj1 = valid ? VxeB[(size_t)j * H_ + colB] : 0.f;
      float t0 = acc0[r] + add0 + vj0;
      float t1 = acc1[r] + add1 + vj1;
      if (valid) {
        size_t o = ((size_t)bi * N_ + j) * H_;
        ((unsigned short*)etmp)[o + colA] = f2b(t0);
        ((unsigned short*)etmp)[o + colB] = f2b(t1);
      }
      float g0 = sqm / (1.f + __expf(-t0));
      float g1 = sqm / (1.f + __expf(-t1));
      float vx0 = valid ? VxB[(size_t)j * H_ + colA] : 0.f;
      float vx1 = valid ? VxB[(size_t)j * H_ + colB] : 0.f;
      agg0 = fmaf(g0, vx0, agg0);
      agg1 = fmaf(g1, vx1, agg1);
      den0 += g0; den1 += g1;
      s1a = fmaf(t0, sqm, s1a);
      s1b = fmaf(t1, sqm, s1b);
      s2a = fmaf(t0 * sqm, t0, s2a);
      s2b = fmaf(t1 * sqm, t1, s2b);
    }
  }
#pragma unroll
  for (int d = 16; d <= 32; d <<= 1) {
    agg0 += __shfl_xor(agg0, d); agg1 += __shfl_xor(agg1, d);
    den0 += __shfl_xor(den0, d); den1 += __shfl_xor(den1, d);
    s1a += __shfl_xor(s1a, d);   s1b += __shfl_xor(s1b, d);
    s2a += __shfl_xor(s2a, d);   s2b += __shfl_xor(s2b, d);
  }
  if ((lane >> 4) == 0) {
    float* ps = pS + (size_t)blockIdx.x * 256;
    ps[colA] = s1a;
    ps[colB] = s1b;
    ps[128 + colA] = s2a;
    ps[128 + colB] = s2b;
    if (DO_X) {
      size_t po = ((size_t)jh * BN_ + bi) * H_;
      pAgg[po + colA] = agg0;
      pAgg[po + colB] = agg1;
      pDen[po + colA] = den0;
      pDen[po + colB] = den1;
    }
  }
}

// ---------------- xtmp finalize (sum jh partials) ----------------

__global__ __launch_bounds__(128) void k_xfin(
    const float* __restrict__ pAgg, const float* __restrict__ pDen,
    const float* __restrict__ Ux, float* __restrict__ xtmp) {
  int bi = blockIdx.x, h = threadIdx.x;
  float a0 = pAgg[(size_t)bi * H_ + h];
  float a1 = pAgg[((size_t)BN_ + bi) * H_ + h];
  float a2 = pAgg[((size_t)2 * BN_ + bi) * H_ + h];
  float a3 = pAgg[((size_t)3 * BN_ + bi) * H_ + h];
  float d0 = pDen[(size_t)bi * H_ + h];
  float d1 = pDen[((size_t)BN_ + bi) * H_ + h];
  float d2 = pDen[((size_t)2 * BN_ + bi) * H_ + h];
  float d3 = pDen[((size_t)3 * BN_ + bi) * H_ + h];
  float a = (a0 + a1) + (a2 + a3);
  float d = (d0 + d1) + (d2 + d3);
  xtmp[(size_t)bi * H_ + h] = Ux[(size_t)bi * H_ + h] + a / (1e-20f + d);
}

// ---------------- reduce partials -> sums (few atomics) ----------------
// blocks 0..31: BN-E (pS over 3200 blocks). blocks 32..63: BN-N (xtmp).

__global__ __launch_bounds__(256) void k_red(
    const float* __restrict__ pS, const float* __restrict__ xtmp,
    const float* __restrict__ mask, float* __restrict__ sums, int doN) {
  int g = blockIdx.x, t = threadIdx.x;
  if (g < 32) {
    float acc = 0.f;
    for (int blk = g * (NBLK_ / 32); blk < (g + 1) * (NBLK_ / 32); ++blk)
      acc += pS[(size_t)blk * 256 + t];
    atomicAdd(&sums[t], acc);
  } else if (doN) {
    int g2 = g - 32;
    int col = t & 127;
    bool sq = t >= 128;
    float acc = 0.f;
    for (int bi = g2 * (BN_ / 32); bi < (g2 + 1) * (BN_ / 32); ++bi) {
      float mi = mask[bi];
      float xt = xtmp[(size_t)bi * H_ + col];
      acc += (sq ? xt * xt : xt) * mi;
    }
    atomicAdd(&sums[256 + t], acc);
  }
}

// ---------------- head: A = e + relu(bnE(etmp)); y = relu(A@U+bU)@V + bV --

__global__ __launch_bounds__(256, 3) void k_head(
    const bf16* __restrict__ e, const bf16* __restrict__ etmp,
    const float* __restrict__ sumsPrev, const float* __restrict__ cnts,
    const float* __restrict__ gEp, const float* __restrict__ bEp,
    const bf16* __restrict__ UT, const float* __restrict__ Ub,
    const float* __restrict__ Vw, const float* __restrict__ Vb,
    const float* __restrict__ mask, float* __restrict__ y) {
  __shared__ __align__(16) char sA[MAXROWS_ * 256];
  __shared__ float part[4][MAXROWS_][2];
  __shared__ float ssE_s[256];
  const int bi = blockIdx.x >> 2;
  const int jh = blockIdx.x & 3;
  const int mt0 = (jh == 0) ? 0 : 3 * jh + 1;
  const int mt1 = 3 * jh + 4;
  const int b = bi / N_;
  const int t = threadIdx.x;
  const int lane = t & 63;
  const int w = t >> 6;
  const float mask_i = mask[bi];

  {
    int h = t & 127;
    float cntE = cnts[1];
    float mE = sumsPrev[h] / cntE;
    float vE = sumsPrev[128 + h] / cntE - mE * mE;
    float scE = gEp[h] * rsqrtf(vE + 1e-5f);
    ssE_s[t] = (t < 128) ? scE : (bEp[h] - mE * scE);
    __syncthreads();
  }

  const int colA = (w << 5) + (lane & 15);
  const int colB = colA + 16;
  const int kgrp = (lane >> 4) << 3;
  const short* wp0 = (const short*)UT + colA * H_ + kgrp;
  const short* wp1 = (const short*)UT + colB * H_ + kgrp;
  short8_t bfA0 = *(const short8_t*)(wp0);
  short8_t bfA1 = *(const short8_t*)(wp0 + 32);
  short8_t bfA2 = *(const short8_t*)(wp0 + 64);
  short8_t bfA3 = *(const short8_t*)(wp0 + 96);
  short8_t bfB0 = *(const short8_t*)(wp1);
  short8_t bfB1 = *(const short8_t*)(wp1 + 32);
  short8_t bfB2 = *(const short8_t*)(wp1 + 64);
  short8_t bfB3 = *(const short8_t*)(wp1 + 96);

  {
    const int nrt = (mt1 - mt0) << 4;
    const unsigned short* eb = (const unsigned short*)e + (size_t)bi * N_ * H_;
    const unsigned short* tb =
        (const unsigned short*)etmp + (size_t)bi * N_ * H_;
    for (int q4 = t; q4 < nrt * 32; q4 += 256) {
      int lr = q4 >> 5, k0 = (q4 & 31) << 2;
      int row = (mt0 << 4) + lr;
      float v0 = 0.f, v1 = 0.f, v2 = 0.f, v3 = 0.f;
      if (row < N_) {
        ushort4 e4 = *(const ushort4*)(eb + row * H_ + k0);
        ushort4 t4 = *(const ushort4*)(tb + row * H_ + k0);
        float mj = mask[b * N_ + row];
        bool msk = (mask_i * mj) > 0.f;
        float sc0 = ssE_s[k0 + 0], sc1 = ssE_s[k0 + 1];
        float sc2 = ssE_s[k0 + 2], sc3 = ssE_s[k0 + 3];
        float sh0 = ssE_s[128 + k0 + 0], sh1 = ssE_s[128 + k0 + 1];
        float sh2 = ssE_s[128 + k0 + 2], sh3 = ssE_s[128 + k0 + 3];
        float f0 = b2f16(t4.x), f1 = b2f16(t4.y);
        float f2 = b2f16(t4.z), f3 = b2f16(t4.w);
        v0 = b2f16(e4.x) + fmaxf(msk ? fmaf(f0, sc0, sh0) : f0, 0.f);
        v1 = b2f16(e4.y) + fmaxf(msk ? fmaf(f1, sc1, sh1) : f1, 0.f);
        v2 = b2f16(e4.z) + fmaxf(msk ? fmaf(f2, sc2, sh2) : f2, 0.f);
        v3 = b2f16(e4.w) + fmaxf(msk ? fmaf(f3, sc3, sh3) : f3, 0.f);
      }
      unsigned int p0 = ((unsigned int)f2b(v1) << 16) | f2b(v0);
      unsigned int p1 = ((unsigned int)f2b(v3) << 16) | f2b(v2);
      unsigned long long pk = ((unsigned long long)p1 << 32) | p0;
      int byo = (lr << 8) + ((k0 * 2) ^ ((lr & 7) << 4));
      *(unsigned long long*)(sA + byo) = pk;
    }
  }
  __syncthreads();

  float bu0 = Ub[colA], bu1 = Ub[colB];
  float v00 = Vw[colA * 2], v01 = Vw[colA * 2 + 1];
  float v10 = Vw[colB * 2], v11 = Vw[colB * 2 + 1];
  const int kb = (lane >> 4) << 4;

  for (int mt = mt0; mt < mt1; ++mt) {
    f32x4 acc0 = {0.f, 0.f, 0.f, 0.f}, acc1 = {0.f, 0.f, 0.f, 0.f};
    int ra = ((mt - mt0) << 4) + (lane & 15);
    const char* ap = sA + (ra << 8);
    int sw = (ra & 7) << 4;
    short8_t av;
    av = *(const short8_t*)(ap + ((kb + 0) ^ sw));
    acc0 = __builtin_amdgcn_mfma_f32_16x16x32_bf16(av, bfA0, acc0, 0, 0, 0);
    acc1 = __builtin_amdgcn_mfma_f32_16x16x32_bf16(av, bfB0, acc1, 0, 0, 0);
    av = *(const short8_t*)(ap + ((kb + 64) ^ sw));
    acc0 = __builtin_amdgcn_mfma_f32_16x16x32_bf16(av, bfA1, acc0, 0, 0, 0);
    acc1 = __builtin_amdgcn_mfma_f32_16x16x32_bf16(av, bfB1, acc1, 0, 0, 0);
    av = *(const short8_t*)(ap + ((kb + 128) ^ sw));
    acc0 = __builtin_amdgcn_mfma_f32_16x16x32_bf16(av, bfA2, acc0, 0, 0, 0);
    acc1 = __builtin_amdgcn_mfma_f32_16x16x32_bf16(av, bfB2, acc1, 0, 0, 0);
    av = *(const short8_t*)(ap + ((kb + 192) ^ sw));
    acc0 = __builtin_amdgcn_mfma_f32_16x16x32_bf16(av, bfA3, acc0, 0, 0, 0);
    acc1 = __builtin_amdgcn_mfma_f32_16x16x32_bf16(av, bfB3, acc1, 0, 0, 0);
#pragma unroll
    for (int r = 0; r < 4; ++r) {
      float h0v = fmaxf(acc0[r] + bu0, 0.f);
      float h1v = fmaxf(acc1[r] + bu1, 0.f);
      float p0 = h0v * v00 + h1v * v10;
      float p1 = h0v * v01 + h1v * v11;
#pragma unroll
      for (int d = 1; d < 16; d <<= 1) {
        p0 += __shfl_xor(p0, d);
        p1 += __shfl_xor(p1, d);
      }
      int jl = ((mt - mt0) << 4) + ((lane >> 4) << 2) + r;
      if ((lane & 15) == 0) { part[w][jl][0] = p0; part[w][jl][1] = p1; }
    }
  }
  __syncthreads();
  float vb0 = Vb[0], vb1 = Vb[1];
  const int nrt = (mt1 - mt0) << 4;
  for (int q = t; q < nrt * 2; q += 256) {
    int jl = q >> 1, c = q & 1;
    int j = (mt0 << 4) + jl;
    if (j < N_) {
      float s = part[0][jl][c] + part[1][jl][c] + part[2][jl][c] +
                part[3][jl][c] + (c ? vb1 : vb0);
      y[((size_t)bi * N_ + j) * 2 + c] = s;
    }
  }
}

// ---------------- launch ----------------

extern "C" void kernel_launch(void* const* d_in, const int* in_sizes, int n_in,
                              void* d_out, int out_size, void* d_ws,
                              size_t ws_size, hipStream_t stream) {
  const int*   x_edges = (const int*)d_in[0];
  const float* ev      = (const float*)d_in[1];
  const float* coord   = (const float*)d_in[2];
  const float* mask    = (const float*)d_in[3];
  const float* w_coord = (const float*)d_in[4];
  const float* w_eval  = (const float*)d_in[5];
  const float* emb     = (const float*)d_in[6];
  const float* eUw = (const float*)d_in[7];
  const float* eUb = (const float*)d_in[8];
  const float* eVw = (const float*)d_in[9];
  const float* eVb = (const float*)d_in[10];
  const float* nUw = (const float*)d_in[11];
  const float* nUb = (const float*)d_in[12];
  const float* nVw = (const float*)d_in[13];
  const float* nVb = (const float*)d_in[14];
  const float* gE  = (const float*)d_in[15];
  const float* bE  = (const float*)d_in[16];
  const float* gN  = (const float*)d_in[17];
  const float* bN  = (const float*)d_in[18];
  const float* mUw = (const float*)d_in[19];
  const float* mUb = (const float*)d_in[20];
  const float* mVw = (const float*)d_in[21];
  const float* mVb = (const float*)d_in[22];

  char* ws = (char*)d_ws;
  size_t off = 0;
  auto alloc = [&](size_t bytes) {
    void* p = ws + off;
    off += (bytes + 255) & ~(size_t)255;
    return p;
  };
  bf16* e     = (bf16*)alloc((size_t)B_ * N_ * N_ * H_ * 2);   // 40.96 MB
  bf16* etmp  = (bf16*)alloc((size_t)B_ * N_ * N_ * H_ * 2);   // 40.96 MB
  float* x    = (float*)alloc((size_t)BN_ * H_ * 4);
  float* Vxe  = (float*)alloc((size_t)BN_ * H_ * 4);
  float* Ux   = (float*)alloc((size_t)BN_ * H_ * 4);
  float* Vx   = (float*)alloc((size_t)BN_ * H_ * 4);
  float* xtmp = (float*)alloc((size_t)BN_ * H_ * 4);
  float* pS   = (float*)alloc((size_t)NBLK_ * 256 * 4);        // 3.28 MB
  float* pAgg = (float*)alloc((size_t)JT_ * BN_ * H_ * 4);     // 1.64 MB
  float* pDen = (float*)alloc((size_t)JT_ * BN_ * H_ * 4);     // 1.64 MB
  float* sums = (float*)alloc(3 * 512 * 4);  // 3 layers x [s1E,s2E,s1N,s2N]
  float* cnts = (float*)alloc(256);
  bf16* WT    = (bf16*)alloc((size_t)4 * H_ * H_ * 2);

  hipMemsetAsync(sums, 0, 3 * 512 * 4, stream);
  k_prep_w<<<4, 256, 0, stream>>>(eUw, mUw, WT);
  k_init_x<<<BN_, 128, 0, stream>>>(coord, w_coord, x);
  k_cnt<<<1, 256, 0, stream>>>(mask, cnts);

  float* sums0 = sums;
  float* sums1 = sums + 512;
  float* sums2 = sums + 1024;

  // layer 0
  k_node_lin<0><<<BN_, 128, 0, stream>>>(
      x, xtmp, sums0, cnts, gN, bN, eVw, eVb, nUw, nUb, nVw, nVb, mask, Vxe,
      Ux, Vx);
  k_edge<0, true><<<NBLK_, 256, 0, stream>>>(
      e, etmp, sums0, cnts, gE, bE, x_edges, ev, w_eval, emb, WT, eUb, Vxe,
      Vx, mask, pS, pAgg, pDen);
  k_xfin<<<BN_, 128, 0, stream>>>(pAgg, pDen, Ux, xtmp);
  k_red<<<64, 256, 0, stream>>>(pS, xtmp, mask, sums0, 1);
  // layer 1
  k_node_lin<1><<<BN_, 128, 0, stream>>>(
      x, xtmp, sums0, cnts, gN, bN, eVw + H_ * H_, eVb + H_, nUw + H_ * H_,
      nUb + H_, nVw + H_ * H_, nVb + H_, mask, Vxe, Ux, Vx);
  k_edge<2, true><<<NBLK_, 256, 0, stream>>>(
      e, etmp, sums0, cnts, gE, bE, x_edges, ev, w_eval, emb, WT + H_ * H_,
      eUb + H_, Vxe, Vx, mask, pS, pAgg, pDen);
  k_xfin<<<BN_, 128, 0, stream>>>(pAgg, pDen, Ux, xtmp);
  k_red<<<64, 256, 0, stream>>>(pS, xtmp, mask, sums1, 1);
  // layer 2
  k_node_lin<1><<<BN_, 128, 0, stream>>>(
      x, xtmp, sums1, cnts, gN + H_, bN + H_, eVw + 2 * H_ * H_,
      eVb + 2 * H_, nUw + 2 * H_ * H_, nUb + 2 * H_, nVw + 2 * H_ * H_,
      nVb + 2 * H_, mask, Vxe, Ux, Vx);
  k_edge<1, false><<<NBLK_, 256, 0, stream>>>(
      e, etmp, sums1, cnts, gE + H_, bE + H_, x_edges, ev, w_eval, emb,
      WT + 2 * H_ * H_, eUb + 2 * H_, Vxe, Vx, mask, pS, pAgg, pDen);
  k_red<<<64, 256, 0, stream>>>(pS, xtmp, mask, sums2, 0);
  // head
  k_head<<<NBLK_, 256, 0, stream>>>(e, etmp, sums2, cnts, gE + 2 * H_,
                                    bE + 2 * H_, WT + (size_t)3 * H_ * H_,
                                    mUb, mVw, mVb, mask, (float*)d_out);
}